// Round 11
// baseline (222.646 us; speedup 1.0000x reference)
//
#include <hip/hip_runtime.h>
#include <stdint.h>

typedef unsigned short u16;
typedef __bf16 bf16x8 __attribute__((ext_vector_type(8)));
typedef float f32x4 __attribute__((ext_vector_type(4)));
typedef u16 u16x8 __attribute__((ext_vector_type(8)));
typedef u16 u16x4 __attribute__((ext_vector_type(4)));
typedef unsigned u32x4 __attribute__((ext_vector_type(4)));

// B=2, S=2048, D=1024, H=16, HD=64, R=4. MS = B*S = 4096.
// QKs layout: [4096][2176] = [Q_p (1024) | K_p (1024) | q_s (64) | k_s (64)]

__device__ __forceinline__ u16 f2bf(float f) {
  unsigned u = __builtin_bit_cast(unsigned, f);
  u += 0x7FFFu + ((u >> 16) & 1u);          // RNE
  return (u16)(u >> 16);
}
__device__ __forceinline__ unsigned cvtpk(float lo, float hi) {
  unsigned r;
  asm("v_cvt_pk_bf16_f32 %0, %1, %2" : "=v"(r) : "v"(lo), "v"(hi));
  return r;
}
__device__ __forceinline__ void gld_lds16(const void* g, void* l) {
  __builtin_amdgcn_global_load_lds((__attribute__((address_space(1))) void*)(g),
                                   (__attribute__((address_space(3))) void*)(l),
                                   16, 0, 0);
}

// ---------------- x -> bf16 ----------------
__global__ __launch_bounds__(256) void k_conv_x(const float* __restrict__ x,
                                                u16* __restrict__ xb) {
  const int i = blockIdx.x * 256 + threadIdx.x;
  const float4* p = reinterpret_cast<const float4*>(x) + (size_t)i * 2;
  float4 a = p[0], b = p[1];
  u16x8 o;
  o[0] = f2bf(a.x); o[1] = f2bf(a.y); o[2] = f2bf(a.z); o[3] = f2bf(a.w);
  o[4] = f2bf(b.x); o[5] = f2bf(b.y); o[6] = f2bf(b.z); o[7] = f2bf(b.w);
  *reinterpret_cast<u16x8*>(xb + (size_t)i * 8) = o;
}

// ---------------- fused big transposes: 4x (1024x1024), z = job ----------------
__global__ __launch_bounds__(256)
void k_tr_big(const float* __restrict__ wq_p, const float* __restrict__ wk_p,
              const float* __restrict__ wv_p, const float* __restrict__ wo_p,
              u16* __restrict__ Wall, u16* __restrict__ Wvt, u16* __restrict__ Bto) {
  __shared__ float tile[32][33];
  const int tx = threadIdx.x & 31, ty = threadIdx.x >> 5;   // 32x8
  const int n0 = blockIdx.x * 32, k0 = blockIdx.y * 32;
  const float* src; u16* dst; int ldd;
  switch (blockIdx.z) {
    case 0: src = wq_p; dst = Wall;                       ldd = 1024; break;
    case 1: src = wk_p; dst = Wall + (size_t)1024 * 1024; ldd = 1024; break;
    case 2: src = wv_p; dst = Wvt;                        ldd = 1024; break;
    default: src = wo_p; dst = Bto;                       ldd = 1088; break;
  }
  #pragma unroll
  for (int i = 0; i < 4; ++i)
    tile[ty + i * 8][tx] = src[(size_t)(k0 + ty + i * 8) * 1024 + n0 + tx];
  __syncthreads();
  #pragma unroll
  for (int i = 0; i < 4; ++i)
    dst[(size_t)(n0 + ty + i * 8) * ldd + k0 + tx] = f2bf(tile[tx][ty + i * 8]);
}

// ---------------- fused small transposes: 4 jobs of 64 tiles, z = job ----------------
__global__ __launch_bounds__(256)
void k_tr_small(const float* __restrict__ wq_s, const float* __restrict__ wk_s,
                const float* __restrict__ wv_s, const float* __restrict__ wo_s,
                const float* __restrict__ wcr,
                u16* __restrict__ Wall, u16* __restrict__ Wvst, u16* __restrict__ Bto) {
  __shared__ float tile[32][33];
  const int tx = threadIdx.x & 31, ty = threadIdx.x >> 5;   // 32x8
  const int tid = blockIdx.x;                               // 64 tiles per job
  const float* src; u16* dst; int N, ldd, ntx; float sc;
  switch (blockIdx.z) {
    case 0: src = wq_s; dst = Wall + (size_t)2048 * 1024; N = 64;   ldd = 1024; ntx = 2;  sc = 1.f; break;
    case 1: src = wk_s; dst = Wall + (size_t)2112 * 1024; N = 64;   ldd = 1024; ntx = 2;  sc = 1.f; break;
    case 2: src = wv_s; dst = Wvst;                       N = 64;   ldd = 1024; ntx = 2;  sc = 1.f; break;
    default: src = wo_s; dst = Bto + 1024;                N = 1024; ldd = 1088; ntx = 32; sc = wcr[0]; break;
  }
  const int n0 = (tid % ntx) * 32, k0 = (tid / ntx) * 32;
  #pragma unroll
  for (int i = 0; i < 4; ++i)
    tile[ty + i * 8][tx] = src[(size_t)(k0 + ty + i * 8) * N + n0 + tx];
  __syncthreads();
  #pragma unroll
  for (int i = 0; i < 4; ++i)
    dst[(size_t)(n0 + ty + i * 8) * ldd + k0 + tx] = f2bf(tile[tx][ty + i * 8] * sc);
}

// ---------------- bias prep: ballqk[2176] + bfin[1024] ----------------
__global__ __launch_bounds__(256)
void k_prep_bias(const float* bq_p, const float* bk_p,
                 const float* bq_s, const float* bk_s,
                 const float* bo_p, const float* bo_s, const float* wcr,
                 float* ballqk, float* bfin) {
  const int i = blockIdx.x * 256 + threadIdx.x;
  if (i < 1024)       ballqk[i] = bq_p[i];
  else if (i < 2048)  ballqk[i] = bk_p[i - 1024];
  else if (i < 2112)  ballqk[i] = bq_s[i - 2048];
  else if (i < 2176)  ballqk[i] = bk_s[i - 2112];
  if (i < 1024) bfin[i] = bo_p[i] + wcr[0] * bo_s[i];
}

// ---------------- GEMM: C[M=4096][N] = A[M][K]bf16 @ Bt[N][K]bf16^T + bias ----------------
// BM=128, BK=32, double-buffered single-barrier k-loop.
// OUTMODE: 0 = bf16 [row][ldc], 1 = bf16 transposed [b][h][d][s] (head dim OHD), 2 = fp32.
template <int BN, int WAVES_M, int OUTMODE, int OHD = 64>
__global__ __launch_bounds__(256, 2)
void k_gemm_bt(const u16* __restrict__ A, int lda,
               const u16* __restrict__ Bt, int ldb,
               const float* __restrict__ bias,
               void* __restrict__ Cv, int ldc, int K) {
  constexpr int WM = 128 / WAVES_M;
  constexpr int MF = WM / 16;
  __shared__ __attribute__((aligned(16))) u16 Atile[2][128 * 32];
  __shared__ __attribute__((aligned(16))) u16 Btile[2][BN * 32];
  const int t = threadIdx.x, w = t >> 6;
  const int lane = t & 63, l4 = lane & 15, g = lane >> 4;
  const int wr = (WAVES_M == 4) ? w : (w >> 1);
  const int wc = (WAVES_M == 4) ? 0 : (w & 1);
  const int m0 = blockIdx.x * 128, n0 = blockIdx.y * BN;

  auto stage = [&](int buf, int kt) {
    const int k0 = kt * 32;
    #pragma unroll
    for (int r = 0; r < 2; ++r) {
      const int slot = r * 256 + t;
      const int row = slot >> 2, blk = slot & 3;
      const int srcb = blk ^ ((row >> 1) & 3);
      gld_lds16(A + (size_t)(m0 + row) * lda + k0 + srcb * 8,
                &Atile[buf][(r * 256 + w * 64) * 8]);
    }
    #pragma unroll
    for (int r = 0; r < BN / 64; ++r) {
      const int slot = r * 256 + t;
      const int row = slot >> 2, blk = slot & 3;
      const int srcb = blk ^ ((row >> 1) & 3);
      gld_lds16(Bt + (size_t)(n0 + row) * ldb + k0 + srcb * 8,
                &Btile[buf][(r * 256 + w * 64) * 8]);
    }
  };

  const f32x4 vz = {0.f, 0.f, 0.f, 0.f};
  f32x4 acc[MF][4];
  #pragma unroll
  for (int mi = 0; mi < MF; ++mi)
    #pragma unroll
    for (int ni = 0; ni < 4; ++ni) acc[mi][ni] = vz;

  const int nkt = K >> 5;
  stage(0, 0);
  __syncthreads();
  for (int kt = 0; kt < nkt; ++kt) {
    const int cur = kt & 1;
    if (kt + 1 < nkt) stage(cur ^ 1, kt + 1);   // prefetch overlaps compute below
    bf16x8 af[MF], bfv[4];
    #pragma unroll
    for (int mi = 0; mi < MF; ++mi) {
      const int row = wr * WM + mi * 16 + l4;
      const int blk = g ^ ((row >> 1) & 3);
      af[mi] = *reinterpret_cast<const bf16x8*>(&Atile[cur][row * 32 + blk * 8]);
    }
    #pragma unroll
    for (int ni = 0; ni < 4; ++ni) {
      const int row = wc * 64 + ni * 16 + l4;
      const int blk = g ^ ((row >> 1) & 3);
      bfv[ni] = *reinterpret_cast<const bf16x8*>(&Btile[cur][row * 32 + blk * 8]);
    }
    #pragma unroll
    for (int mi = 0; mi < MF; ++mi)
      #pragma unroll
      for (int ni = 0; ni < 4; ++ni)
        acc[mi][ni] = __builtin_amdgcn_mfma_f32_16x16x32_bf16(af[mi], bfv[ni],
                                                              acc[mi][ni], 0, 0, 0);
    __syncthreads();   // drains prefetch + all waves done with buf[cur]
  }
  // epilogue. C/D layout: col = lane&15, row = (lane>>4)*4 + reg
  #pragma unroll
  for (int mi = 0; mi < MF; ++mi) {
    #pragma unroll
    for (int ni = 0; ni < 4; ++ni) {
      const int grow0 = m0 + wr * WM + mi * 16 + g * 4;
      const int gcol = n0 + wc * 64 + ni * 16 + l4;
      const float bb = bias ? bias[gcol] : 0.f;
      if constexpr (OUTMODE == 1) {
        const int bidx = grow0 >> 11, s0 = grow0 & 2047;
        const int hh = gcol / OHD, dd = gcol % OHD;
        u16x4 ov;
        #pragma unroll
        for (int r = 0; r < 4; ++r) ov[r] = f2bf(acc[mi][ni][r] + bb);
        *reinterpret_cast<u16x4*>((u16*)Cv +
            (size_t)((bidx * 16 + hh) * OHD + dd) * 2048 + s0) = ov;
      } else {
        #pragma unroll
        for (int r = 0; r < 4; ++r) {
          const float v = acc[mi][ni][r] + bb;
          if constexpr (OUTMODE == 0)
            ((u16*)Cv)[(size_t)(grow0 + r) * ldc + gcol] = f2bf(v);
          else
            ((float*)Cv)[(size_t)(grow0 + r) * ldc + gcol] = v;
        }
      }
    }
  }
}

// ---------------- primary flash attention: swapped QK^T + permuted K rows ----------------
// In-register P, no Plds. Wave w owns 64 q-rows (mi=0..3) of a 256-row q-tile -> K/V LDS
// reads per q-row HALVED vs 32-row waves. Grid 256 (1 block/CU), XCD-swizzled bijectively.
__global__ __launch_bounds__(256, 1)
void k_attn_primary(const u16* __restrict__ QKs, const u16* __restrict__ Vpt,
                    u16* __restrict__ Ao) {
  __shared__ __attribute__((aligned(16))) u16 Klds[2][64 * 64];
  __shared__ __attribute__((aligned(16))) u16 Vlds[2][64 * 64];
  const int t = threadIdx.x, w = t >> 6;
  const int lane = t & 63, l4 = lane & 15, g = lane >> 4;
  const int id = blockIdx.x;
  const int lin = (id & 7) * 32 + (id >> 3);   // 256 blocks, 256%8==0 -> bijective
  const int qt = lin & 7, hb = lin >> 3;       // each XCD: 4 whole (b,h) groups
  const int h = hb & 15, b = hb >> 4;
  const int q0 = qt * 256;

  const u16* Qbase = QKs + (size_t)(b * 2048 + q0) * 2176 + h * 64;
  const u16* Kbase = QKs + (size_t)(b * 2048) * 2176 + 1024 + h * 64;
  const u16* Vbase = Vpt + (size_t)((b * 16 + h) * 64) * 2048;

  #pragma unroll
  for (int r = 0; r < 2; ++r) {  // K (row-permuted), V tile 0 -> buf 0
    const int sl = r * 256 + t, row = sl >> 3, blk = sl & 7;
    const int srcb = blk ^ (row & 7);
    const int prow = (row & 32) | (((row >> 2) & 3) << 3) | (((row >> 4) & 1) << 2) | (row & 3);
    gld_lds16(Kbase + (size_t)prow * 2176 + srcb * 8, &Klds[0][(r * 256 + w * 64) * 8]);
    gld_lds16(Vbase + (size_t)row * 2048 + srcb * 8, &Vlds[0][(r * 256 + w * 64) * 8]);
  }

  bf16x8 aq[4][2];  // Q frags direct from global: row w*64+mi*16+l4, d = kd*32+g*8..+7
  #pragma unroll
  for (int mi = 0; mi < 4; ++mi)
    #pragma unroll
    for (int kd = 0; kd < 2; ++kd)
      aq[mi][kd] = *reinterpret_cast<const bf16x8*>(
          Qbase + (size_t)(w * 64 + mi * 16 + l4) * 2176 + kd * 32 + g * 8);

  __syncthreads();

  const f32x4 vz = {0.f, 0.f, 0.f, 0.f};
  float l_r[4] = {0.f, 0.f, 0.f, 0.f};
  f32x4 acc_o[4][4];
  #pragma unroll
  for (int mi = 0; mi < 4; ++mi)
    #pragma unroll
    for (int nd = 0; nd < 4; ++nd) acc_o[mi][nd] = vz;

  for (int kt = 0; kt < 32; ++kt) {
    const int cur = kt & 1;
    if (kt < 31) {  // prefetch next K/V tile into other buffer (overlaps compute)
      const int kn = kt + 1;
      #pragma unroll
      for (int r = 0; r < 2; ++r) {
        const int sl = r * 256 + t, row = sl >> 3, blk = sl & 7;
        const int srcb = blk ^ (row & 7);
        const int prow = (row & 32) | (((row >> 2) & 3) << 3) | (((row >> 4) & 1) << 2) | (row & 3);
        gld_lds16(Kbase + (size_t)(kn * 64 + prow) * 2176 + srcb * 8,
                  &Klds[cur ^ 1][(r * 256 + w * 64) * 8]);
        gld_lds16(Vbase + (size_t)row * 2048 + kn * 64 + srcb * 8,
                  &Vlds[cur ^ 1][(r * 256 + w * 64) * 8]);
      }
    }
    // S^T = mfma(K_frag, Q_frag): one K-fragment read feeds 4 mi (64 q-rows)
    f32x4 sc[4][4];
    #pragma unroll
    for (int mi = 0; mi < 4; ++mi)
      #pragma unroll
      for (int ni = 0; ni < 4; ++ni) sc[mi][ni] = vz;
    #pragma unroll
    for (int kd = 0; kd < 2; ++kd) {
      bf16x8 bk[4];
      #pragma unroll
      for (int ni = 0; ni < 4; ++ni) {
        const int row = ni * 16 + l4;
        const int blk = (kd * 4 + g) ^ (row & 7);
        bk[ni] = *reinterpret_cast<const bf16x8*>(&Klds[cur][row * 64 + blk * 8]);
      }
      #pragma unroll
      for (int mi = 0; mi < 4; ++mi)
        #pragma unroll
        for (int ni = 0; ni < 4; ++ni)
          sc[mi][ni] = __builtin_amdgcn_mfma_f32_16x16x32_bf16(bk[ni], aq[mi][kd],
                                                               sc[mi][ni], 0, 0, 0);
    }
    // in-register softmax
    unsigned pw[4][4][2];
    #pragma unroll
    for (int mi = 0; mi < 4; ++mi) {
      float rs = 0.f;
      #pragma unroll
      for (int ni = 0; ni < 4; ++ni) {
        const float a0 = __expf(sc[mi][ni][0] * 0.125f);
        const float a1 = __expf(sc[mi][ni][1] * 0.125f);
        const float a2 = __expf(sc[mi][ni][2] * 0.125f);
        const float a3 = __expf(sc[mi][ni][3] * 0.125f);
        rs += (a0 + a1) + (a2 + a3);
        pw[mi][ni][0] = cvtpk(a0, a1);
        pw[mi][ni][1] = cvtpk(a2, a3);
      }
      rs += __shfl_xor(rs, 16);
      rs += __shfl_xor(rs, 32);
      l_r[mi] += rs;
    }
    // O += P V : one V-fragment read feeds 4 mi
    #pragma unroll
    for (int ks = 0; ks < 2; ++ks) {
      bf16x8 bv[4];
      #pragma unroll
      for (int nd = 0; nd < 4; ++nd) {
        const int row = nd * 16 + l4;
        const int blk = (ks * 4 + g) ^ (row & 7);
        bv[nd] = *reinterpret_cast<const bf16x8*>(&Vlds[cur][row * 64 + blk * 8]);
      }
      #pragma unroll
      for (int mi = 0; mi < 4; ++mi) {
        const u32x4 aw = {pw[mi][2 * ks][0], pw[mi][2 * ks][1],
                          pw[mi][2 * ks + 1][0], pw[mi][2 * ks + 1][1]};
        const bf16x8 ap = __builtin_bit_cast(bf16x8, aw);
        #pragma unroll
        for (int nd = 0; nd < 4; ++nd)
          acc_o[mi][nd] = __builtin_amdgcn_mfma_f32_16x16x32_bf16(ap, bv[nd],
                                                                  acc_o[mi][nd], 0, 0, 0);
      }
    }
    __syncthreads();
  }
  // epilogue
  float linv[4][4];
  #pragma unroll
  for (int mi = 0; mi < 4; ++mi)
    #pragma unroll
    for (int r = 0; r < 4; ++r) {
      const int src = (lane & 48) + ((lane & 48) >> 2) + r;
      linv[mi][r] = 1.0f / __shfl(l_r[mi], src);
    }
  #pragma unroll
  for (int mi = 0; mi < 4; ++mi)
    #pragma unroll
    for (int nd = 0; nd < 4; ++nd)
      #pragma unroll
      for (int r = 0; r < 4; ++r) {
        const int grow = b * 2048 + q0 + w * 64 + mi * 16 + g * 4 + r;
        const int gcol = h * 64 + nd * 16 + l4;
        Ao[(size_t)grow * 1088 + gcol] = f2bf(acc_o[mi][nd][r] * linv[mi][r]);
      }
}

// ---------------- secondary attention (R=4, scale 1/2), MFMA, one-pass no-max ----------------
// Q_s/K_s read from QKs cols 2048..2175 (ld 2176).
__global__ __launch_bounds__(256, 2)
void k_attn_sec(const u16* __restrict__ QKs, const u16* __restrict__ Vst,
                u16* __restrict__ Ao) {
  __shared__ __attribute__((aligned(16))) u16 KsL[2048 * 4];   // [s][d] 16KB
  __shared__ __attribute__((aligned(16))) u16 VtL[5 * 2056];   // rows d0..3 + ones, pad 8
  __shared__ __attribute__((aligned(16))) u16 Plds[4][32 * 64];
  const int t = threadIdx.x, w = t >> 6;
  const int lane = t & 63, l4 = lane & 15, g = lane >> 4;
  const int q0 = blockIdx.x * 128, h = blockIdx.y, b = blockIdx.z;

  const u16* Vsrc = Vst + (size_t)((b * 16 + h) * 4) * 2048;
  #pragma unroll
  for (int r = 0; r < 4; ++r)
    gld_lds16(Vsrc + (size_t)r * 2048 + t * 8, &VtL[r * 2056 + w * 512]);
  {
    u16x8 ones;
    #pragma unroll
    for (int j = 0; j < 8; ++j) ones[j] = 0x3F80;
    *reinterpret_cast<u16x8*>(&VtL[4 * 2056 + t * 8]) = ones;
  }
  #pragma unroll
  for (int i = 0; i < 8; ++i) {
    const int s = i * 256 + t;
    const uint2 kk = *reinterpret_cast<const uint2*>(
        QKs + (size_t)(b * 2048 + s) * 2176 + 2112 + h * 4);
    *reinterpret_cast<uint2*>(&KsL[s * 4]) = kk;
  }
  bf16x8 aq[2];
  #pragma unroll
  for (int mi = 0; mi < 2; ++mi) {
    u16x8 qv = {0, 0, 0, 0, 0, 0, 0, 0};
    if (g == 0) {
      const uint2 qq = *reinterpret_cast<const uint2*>(
          QKs + (size_t)(b * 2048 + q0 + w * 32 + mi * 16 + l4) * 2176 + 2048 + h * 4);
      qv[0] = (u16)(qq.x & 0xffff); qv[1] = (u16)(qq.x >> 16);
      qv[2] = (u16)(qq.y & 0xffff); qv[3] = (u16)(qq.y >> 16);
    }
    aq[mi] = __builtin_bit_cast(bf16x8, qv);
  }
  __syncthreads();

  const f32x4 vz = {0.f, 0.f, 0.f, 0.f};
  f32x4 acc[2];
  acc[0] = vz; acc[1] = vz;

  for (int kt = 0; kt < 32; ++kt) {
    f32x4 sc[2][4];
    bf16x8 bk[4];
    #pragma unroll
    for (int ni = 0; ni < 4; ++ni) {
      u16x8 kv = {0, 0, 0, 0, 0, 0, 0, 0};
      if (g == 0) {
        const uint2 kk = *reinterpret_cast<const uint2*>(
            &KsL[(kt * 64 + ni * 16 + l4) * 4]);
        kv[0] = (u16)(kk.x & 0xffff); kv[1] = (u16)(kk.x >> 16);
        kv[2] = (u16)(kk.y & 0xffff); kv[3] = (u16)(kk.y >> 16);
      }
      bk[ni] = __builtin_bit_cast(bf16x8, kv);
    }
    #pragma unroll
    for (int mi = 0; mi < 2; ++mi)
      #pragma unroll
      for (int ni = 0; ni < 4; ++ni)
        sc[mi][ni] = __builtin_amdgcn_mfma_f32_16x16x32_bf16(aq[mi], bk[ni], vz, 0, 0, 0);
    #pragma unroll
    for (int mi = 0; mi < 2; ++mi)
      #pragma unroll
      for (int r = 0; r < 4; ++r) {
        const int prow = mi * 16 + g * 4 + r;
        #pragma unroll
        for (int ni = 0; ni < 4; ++ni) {
          const float p = __expf(sc[mi][ni][r] * 0.5f);
          const int col = ni * 16 + l4;
          Plds[w][prow * 64 + ((col >> 3) ^ (prow & 7)) * 8 + (col & 7)] = f2bf(p);
        }
      }
    asm volatile("s_waitcnt lgkmcnt(0)" ::: "memory");
    #pragma unroll
    for (int ks = 0; ks < 2; ++ks) {
      const int blko = kt * 8 + ks * 4 + g;
      const int vrow = (l4 < 4) ? l4 : 4;
      const bf16x8 bv = *reinterpret_cast<const bf16x8*>(&VtL[vrow * 2056 + blko * 8]);
      #pragma unroll
      for (int mi = 0; mi < 2; ++mi) {
        const int row = mi * 16 + l4;
        const int blk = (ks * 4 + g) ^ (row & 7);
        const bf16x8 ap = *reinterpret_cast<const bf16x8*>(&Plds[w][row * 64 + blk * 8]);
        acc[mi] = __builtin_amdgcn_mfma_f32_16x16x32_bf16(ap, bv, acc[mi], 0, 0, 0);
      }
    }
  }
  #pragma unroll
  for (int mi = 0; mi < 2; ++mi)
    #pragma unroll
    for (int r = 0; r < 4; ++r) {
      const float lsum = __shfl(acc[mi][r], (lane & 48) + 4);
      if (l4 < 4) {
        const int grow = b * 2048 + q0 + w * 32 + mi * 16 + g * 4 + r;
        Ao[(size_t)grow * 1088 + 1024 + h * 4 + l4] = f2bf(acc[mi][r] / lsum);
      }
    }
}

// ---------------- launch ----------------
extern "C" void kernel_launch(void* const* d_in, const int* in_sizes, int n_in,
                              void* d_out, int out_size, void* d_ws, size_t ws_size,
                              hipStream_t stream) {
  (void)in_sizes; (void)n_in; (void)out_size; (void)ws_size;
  const float* x    = (const float*)d_in[0];
  const float* wq_p = (const float*)d_in[1];
  const float* bq_p = (const float*)d_in[2];
  const float* wk_p = (const float*)d_in[3];
  const float* bk_p = (const float*)d_in[4];
  const float* wv_p = (const float*)d_in[5];
  const float* bv_p = (const float*)d_in[6];
  const float* wo_p = (const float*)d_in[7];
  const float* bo_p = (const float*)d_in[8];
  const float* wq_s = (const float*)d_in[9];
  const float* bq_s = (const float*)d_in[10];
  const float* wk_s = (const float*)d_in[11];
  const float* bk_s = (const float*)d_in[12];
  const float* wv_s = (const float*)d_in[13];
  const float* bv_s = (const float*)d_in[14];
  const float* wo_s = (const float*)d_in[15];
  const float* bo_s = (const float*)d_in[16];
  const float* wcr  = (const float*)d_in[17];

  char* p = (char*)d_ws;
  auto take = [&](size_t bytes) { char* r = p; p += (bytes + 255) & ~(size_t)255; return r; };
  u16* xb      = (u16*)take((size_t)4096 * 1024 * 2);
  u16* Wall    = (u16*)take((size_t)2176 * 1024 * 2);   // [Wq_p|Wk_p|wq_s|wk_s]
  u16* Wvt     = (u16*)take((size_t)1024 * 1024 * 2);
  u16* Wvst    = (u16*)take((size_t)64 * 1024 * 2);
  u16* Bto     = (u16*)take((size_t)1024 * 1088 * 2);
  float* ballqk= (float*)take(2176 * 4);
  float* bfin  = (float*)take(1024 * 4);
  u16* QKs     = (u16*)take((size_t)4096 * 2176 * 2);
  u16* Vpt     = (u16*)take((size_t)4096 * 1024 * 2);
  u16* Vst     = (u16*)take((size_t)2 * 16 * 4 * 2048 * 2);
  u16* Ao      = (u16*)take((size_t)4096 * 1088 * 2);

  k_conv_x<<<2048, 256, 0, stream>>>(x, xb);
  k_tr_big<<<dim3(32, 32, 4), 256, 0, stream>>>(wq_p, wk_p, wv_p, wo_p, Wall, Wvt, Bto);
  k_tr_small<<<dim3(64, 1, 4), 256, 0, stream>>>(wq_s, wk_s, wv_s, wo_s, wcr,
                                                 Wall, Wvst, Bto);
  k_prep_bias<<<9, 256, 0, stream>>>(bq_p, bk_p, bq_s, bk_s, bo_p, bo_s, wcr, ballqk, bfin);

  // fused Q|K|q_s|k_s projection: one contiguous OUTMODE=0 GEMM, N=2176 (=17*128)
  k_gemm_bt<128, 2, 0><<<dim3(32, 17), 256, 0, stream>>>(xb, 1024, Wall, 1024, ballqk,
                                                         QKs, 2176, 1024);
  k_gemm_bt<128, 2, 1, 64><<<dim3(32, 8), 256, 0, stream>>>(xb, 1024, Wvt, 1024, bv_p, Vpt, 0, 1024);
  k_gemm_bt<64, 4, 1, 4><<<dim3(32, 1), 256, 0, stream>>>(xb, 1024, Wvst, 1024, bv_s, Vst, 0, 1024);

  k_attn_primary<<<256, 256, 0, stream>>>(QKs, Vpt, Ao);
  k_attn_sec<<<dim3(16, 16, 2), 256, 0, stream>>>(QKs, Vst, Ao);

  k_gemm_bt<128, 2, 2><<<dim3(32, 8), 256, 0, stream>>>(Ao, 1088, Bto, 1088, bfin, d_out, 1024, 1088);
}

// Round 12
// 200.867 us; speedup vs baseline: 1.1084x; 1.1084x over previous
//
#include <hip/hip_runtime.h>
#include <stdint.h>

typedef unsigned short u16;
typedef __bf16 bf16x8 __attribute__((ext_vector_type(8)));
typedef float f32x4 __attribute__((ext_vector_type(4)));
typedef u16 u16x8 __attribute__((ext_vector_type(8)));
typedef u16 u16x4 __attribute__((ext_vector_type(4)));
typedef unsigned u32x4 __attribute__((ext_vector_type(4)));

// B=2, S=2048, D=1024, H=16, HD=64, R=4. MS = B*S = 4096.
// QKs layout: [4096][2176] = [Q_p (1024) | K_p (1024) | q_s (64) | k_s (64)]

__device__ __forceinline__ u16 f2bf(float f) {
  unsigned u = __builtin_bit_cast(unsigned, f);
  u += 0x7FFFu + ((u >> 16) & 1u);          // RNE
  return (u16)(u >> 16);
}
__device__ __forceinline__ unsigned cvtpk(float lo, float hi) {
  unsigned r;
  asm("v_cvt_pk_bf16_f32 %0, %1, %2" : "=v"(r) : "v"(lo), "v"(hi));
  return r;
}
__device__ __forceinline__ void gld_lds16(const void* g, void* l) {
  __builtin_amdgcn_global_load_lds((__attribute__((address_space(1))) void*)(g),
                                   (__attribute__((address_space(3))) void*)(l),
                                   16, 0, 0);
}

// ---------------- fused prep: conv_x | 4 big transposes | 4 small transposes | bias ------
// grid 6409 x 256: [0,2048) conv_x, [2048,6144) tr_big, [6144,6400) tr_small, [6400,6409) bias
__global__ __launch_bounds__(256)
void k_prep(const float* __restrict__ x,
            const float* __restrict__ wq_p, const float* __restrict__ wk_p,
            const float* __restrict__ wv_p, const float* __restrict__ wo_p,
            const float* __restrict__ wq_s, const float* __restrict__ wk_s,
            const float* __restrict__ wv_s, const float* __restrict__ wo_s,
            const float* __restrict__ bq_p, const float* __restrict__ bk_p,
            const float* __restrict__ bq_s, const float* __restrict__ bk_s,
            const float* __restrict__ bo_p, const float* __restrict__ bo_s,
            const float* __restrict__ wcr,
            u16* __restrict__ xb, u16* __restrict__ Wall, u16* __restrict__ Wvt,
            u16* __restrict__ Wvst, u16* __restrict__ Bto,
            float* __restrict__ ballqk, float* __restrict__ bfin) {
  const int id = blockIdx.x;
  if (id < 2048) {                     // ---- x -> bf16 (proven k_conv_x body)
    const int i = id * 256 + threadIdx.x;
    const float4* p = reinterpret_cast<const float4*>(x) + (size_t)i * 2;
    float4 a = p[0], b = p[1];
    u16x8 o;
    o[0] = f2bf(a.x); o[1] = f2bf(a.y); o[2] = f2bf(a.z); o[3] = f2bf(a.w);
    o[4] = f2bf(b.x); o[5] = f2bf(b.y); o[6] = f2bf(b.z); o[7] = f2bf(b.w);
    *reinterpret_cast<u16x8*>(xb + (size_t)i * 8) = o;
    return;
  }
  if (id < 6400) {                     // ---- transposes (proven tile body)
    __shared__ float tile[32][33];
    const int tx = threadIdx.x & 31, ty = threadIdx.x >> 5;  // 32x8
    const float* src; u16* dst; int N, ldd, n0, k0; float sc = 1.f;
    if (id < 6144) {                   // big: 4 jobs x 1024 tiles (N=1024)
      const int tid = id - 2048, job = tid >> 10, t10 = tid & 1023;
      switch (job) {
        case 0: src = wq_p; dst = Wall;                       ldd = 1024; break;
        case 1: src = wk_p; dst = Wall + (size_t)1024 * 1024; ldd = 1024; break;
        case 2: src = wv_p; dst = Wvt;                        ldd = 1024; break;
        default: src = wo_p; dst = Bto;                       ldd = 1088; break;
      }
      N = 1024; n0 = (t10 & 31) * 32; k0 = (t10 >> 5) * 32;
    } else {                           // small: 4 jobs x 64 tiles
      const int tid = id - 6144, job = tid >> 6, t6 = tid & 63;
      int ntx;
      switch (job) {
        case 0: src = wq_s; dst = Wall + (size_t)2048 * 1024; N = 64;   ldd = 1024; ntx = 2; break;
        case 1: src = wk_s; dst = Wall + (size_t)2112 * 1024; N = 64;   ldd = 1024; ntx = 2; break;
        case 2: src = wv_s; dst = Wvst;                       N = 64;   ldd = 1024; ntx = 2; break;
        default: src = wo_s; dst = Bto + 1024;                N = 1024; ldd = 1088; ntx = 32; sc = wcr[0]; break;
      }
      n0 = (t6 % ntx) * 32; k0 = (t6 / ntx) * 32;
    }
    #pragma unroll
    for (int i = 0; i < 4; ++i)
      tile[ty + i * 8][tx] = src[(size_t)(k0 + ty + i * 8) * N + n0 + tx];
    __syncthreads();
    #pragma unroll
    for (int i = 0; i < 4; ++i)
      dst[(size_t)(n0 + ty + i * 8) * ldd + k0 + tx] = f2bf(tile[tx][ty + i * 8] * sc);
    return;
  }
  // ---- bias prep (proven body)
  const int i = (id - 6400) * 256 + threadIdx.x;
  if (i < 1024)       ballqk[i] = bq_p[i];
  else if (i < 2048)  ballqk[i] = bk_p[i - 1024];
  else if (i < 2112)  ballqk[i] = bq_s[i - 2048];
  else if (i < 2176)  ballqk[i] = bk_s[i - 2112];
  if (i < 1024) bfin[i] = bo_p[i] + wcr[0] * bo_s[i];
}

// ---------------- GEMM: C[M=4096][N] = A[M][K]bf16 @ Bt[N][K]bf16^T + bias ----------------
// BM=128, BK=32, double-buffered single-barrier k-loop.
// OUTMODE: 0 = bf16 [row][ldc], 1 = bf16 transposed [b][h][d][s] (head dim OHD), 2 = fp32.
template <int BN, int WAVES_M, int OUTMODE, int OHD = 64>
__global__ __launch_bounds__(256, 2)
void k_gemm_bt(const u16* __restrict__ A, int lda,
               const u16* __restrict__ Bt, int ldb,
               const float* __restrict__ bias,
               void* __restrict__ Cv, int ldc, int K) {
  constexpr int WM = 128 / WAVES_M;
  constexpr int MF = WM / 16;
  __shared__ __attribute__((aligned(16))) u16 Atile[2][128 * 32];
  __shared__ __attribute__((aligned(16))) u16 Btile[2][BN * 32];
  const int t = threadIdx.x, w = t >> 6;
  const int lane = t & 63, l4 = lane & 15, g = lane >> 4;
  const int wr = (WAVES_M == 4) ? w : (w >> 1);
  const int wc = (WAVES_M == 4) ? 0 : (w & 1);
  const int m0 = blockIdx.x * 128, n0 = blockIdx.y * BN;

  auto stage = [&](int buf, int kt) {
    const int k0 = kt * 32;
    #pragma unroll
    for (int r = 0; r < 2; ++r) {
      const int slot = r * 256 + t;
      const int row = slot >> 2, blk = slot & 3;
      const int srcb = blk ^ ((row >> 1) & 3);
      gld_lds16(A + (size_t)(m0 + row) * lda + k0 + srcb * 8,
                &Atile[buf][(r * 256 + w * 64) * 8]);
    }
    #pragma unroll
    for (int r = 0; r < BN / 64; ++r) {
      const int slot = r * 256 + t;
      const int row = slot >> 2, blk = slot & 3;
      const int srcb = blk ^ ((row >> 1) & 3);
      gld_lds16(Bt + (size_t)(n0 + row) * ldb + k0 + srcb * 8,
                &Btile[buf][(r * 256 + w * 64) * 8]);
    }
  };

  const f32x4 vz = {0.f, 0.f, 0.f, 0.f};
  f32x4 acc[MF][4];
  #pragma unroll
  for (int mi = 0; mi < MF; ++mi)
    #pragma unroll
    for (int ni = 0; ni < 4; ++ni) acc[mi][ni] = vz;

  const int nkt = K >> 5;
  stage(0, 0);
  __syncthreads();
  for (int kt = 0; kt < nkt; ++kt) {
    const int cur = kt & 1;
    if (kt + 1 < nkt) stage(cur ^ 1, kt + 1);   // prefetch overlaps compute below
    bf16x8 af[MF], bfv[4];
    #pragma unroll
    for (int mi = 0; mi < MF; ++mi) {
      const int row = wr * WM + mi * 16 + l4;
      const int blk = g ^ ((row >> 1) & 3);
      af[mi] = *reinterpret_cast<const bf16x8*>(&Atile[cur][row * 32 + blk * 8]);
    }
    #pragma unroll
    for (int ni = 0; ni < 4; ++ni) {
      const int row = wc * 64 + ni * 16 + l4;
      const int blk = g ^ ((row >> 1) & 3);
      bfv[ni] = *reinterpret_cast<const bf16x8*>(&Btile[cur][row * 32 + blk * 8]);
    }
    #pragma unroll
    for (int mi = 0; mi < MF; ++mi)
      #pragma unroll
      for (int ni = 0; ni < 4; ++ni)
        acc[mi][ni] = __builtin_amdgcn_mfma_f32_16x16x32_bf16(af[mi], bfv[ni],
                                                              acc[mi][ni], 0, 0, 0);
    __syncthreads();   // drains prefetch + all waves done with buf[cur]
  }
  // epilogue. C/D layout: col = lane&15, row = (lane>>4)*4 + reg
  #pragma unroll
  for (int mi = 0; mi < MF; ++mi) {
    #pragma unroll
    for (int ni = 0; ni < 4; ++ni) {
      const int grow0 = m0 + wr * WM + mi * 16 + g * 4;
      const int gcol = n0 + wc * 64 + ni * 16 + l4;
      const float bb = bias ? bias[gcol] : 0.f;
      if constexpr (OUTMODE == 1) {
        const int bidx = grow0 >> 11, s0 = grow0 & 2047;
        const int hh = gcol / OHD, dd = gcol % OHD;
        u16x4 ov;
        #pragma unroll
        for (int r = 0; r < 4; ++r) ov[r] = f2bf(acc[mi][ni][r] + bb);
        *reinterpret_cast<u16x4*>((u16*)Cv +
            (size_t)((bidx * 16 + hh) * OHD + dd) * 2048 + s0) = ov;
      } else {
        #pragma unroll
        for (int r = 0; r < 4; ++r) {
          const float v = acc[mi][ni][r] + bb;
          if constexpr (OUTMODE == 0)
            ((u16*)Cv)[(size_t)(grow0 + r) * ldc + gcol] = f2bf(v);
          else
            ((float*)Cv)[(size_t)(grow0 + r) * ldc + gcol] = v;
        }
      }
    }
  }
}

// ---------------- primary flash attention: swapped QK^T + permuted K rows ----------------
// In-register P (cvt_pk pairs -> PV A-frags), no Plds, no fence. Q loaded global->reg
// directly (16B-aligned frags, L2-hot). XCD-swizzled 1D grid (512 blocks, bijective).
__global__ __launch_bounds__(256, 2)
void k_attn_primary(const u16* __restrict__ QKs, const u16* __restrict__ Vpt,
                    u16* __restrict__ Ao) {
  __shared__ __attribute__((aligned(16))) u16 Klds[2][64 * 64];
  __shared__ __attribute__((aligned(16))) u16 Vlds[2][64 * 64];
  const int t = threadIdx.x, w = t >> 6;
  const int lane = t & 63, l4 = lane & 15, g = lane >> 4;
  const int id = blockIdx.x;
  const int lin = (id & 7) * 64 + (id >> 3);
  const int qt = lin & 15, hb = lin >> 4;
  const int h = hb & 15, b = hb >> 4;
  const int q0 = qt * 128;

  const u16* Qbase = QKs + (size_t)(b * 2048 + q0) * 2176 + h * 64;
  const u16* Kbase = QKs + (size_t)(b * 2048) * 2176 + 1024 + h * 64;
  const u16* Vbase = Vpt + (size_t)((b * 16 + h) * 64) * 2048;

  #pragma unroll
  for (int r = 0; r < 2; ++r) {  // K (row-permuted), V tile 0 -> buf 0
    const int sl = r * 256 + t, row = sl >> 3, blk = sl & 7;
    const int srcb = blk ^ (row & 7);
    const int prow = (row & 32) | (((row >> 2) & 3) << 3) | (((row >> 4) & 1) << 2) | (row & 3);
    gld_lds16(Kbase + (size_t)prow * 2176 + srcb * 8, &Klds[0][(r * 256 + w * 64) * 8]);
    gld_lds16(Vbase + (size_t)row * 2048 + srcb * 8, &Vlds[0][(r * 256 + w * 64) * 8]);
  }

  bf16x8 aq[2][2];  // Q frags direct from global: row w*32+mi*16+l4, d = kd*32+g*8..+7
  #pragma unroll
  for (int mi = 0; mi < 2; ++mi)
    #pragma unroll
    for (int kd = 0; kd < 2; ++kd)
      aq[mi][kd] = *reinterpret_cast<const bf16x8*>(
          Qbase + (size_t)(w * 32 + mi * 16 + l4) * 2176 + kd * 32 + g * 8);

  __syncthreads();

  const f32x4 vz = {0.f, 0.f, 0.f, 0.f};
  float l_r[2] = {0.f, 0.f};
  f32x4 acc_o[2][4];
  #pragma unroll
  for (int mi = 0; mi < 2; ++mi)
    #pragma unroll
    for (int nd = 0; nd < 4; ++nd) acc_o[mi][nd] = vz;

  for (int kt = 0; kt < 32; ++kt) {
    const int cur = kt & 1;
    if (kt < 31) {  // prefetch next K/V tile into other buffer (overlaps compute)
      const int kn = kt + 1;
      #pragma unroll
      for (int r = 0; r < 2; ++r) {
        const int sl = r * 256 + t, row = sl >> 3, blk = sl & 7;
        const int srcb = blk ^ (row & 7);
        const int prow = (row & 32) | (((row >> 2) & 3) << 3) | (((row >> 4) & 1) << 2) | (row & 3);
        gld_lds16(Kbase + (size_t)(kn * 64 + prow) * 2176 + srcb * 8,
                  &Klds[cur ^ 1][(r * 256 + w * 64) * 8]);
        gld_lds16(Vbase + (size_t)row * 2048 + kn * 64 + srcb * 8,
                  &Vlds[cur ^ 1][(r * 256 + w * 64) * 8]);
      }
    }
    // S^T = mfma(K_frag, Q_frag)
    f32x4 sc[2][4];
    #pragma unroll
    for (int mi = 0; mi < 2; ++mi)
      #pragma unroll
      for (int ni = 0; ni < 4; ++ni) sc[mi][ni] = vz;
    #pragma unroll
    for (int kd = 0; kd < 2; ++kd) {
      bf16x8 bk[4];
      #pragma unroll
      for (int ni = 0; ni < 4; ++ni) {
        const int row = ni * 16 + l4;
        const int blk = (kd * 4 + g) ^ (row & 7);
        bk[ni] = *reinterpret_cast<const bf16x8*>(&Klds[cur][row * 64 + blk * 8]);
      }
      #pragma unroll
      for (int mi = 0; mi < 2; ++mi)
        #pragma unroll
        for (int ni = 0; ni < 4; ++ni)
          sc[mi][ni] = __builtin_amdgcn_mfma_f32_16x16x32_bf16(bk[ni], aq[mi][kd],
                                                               sc[mi][ni], 0, 0, 0);
    }
    // in-register softmax
    unsigned pw[2][4][2];
    #pragma unroll
    for (int mi = 0; mi < 2; ++mi) {
      float rs = 0.f;
      #pragma unroll
      for (int ni = 0; ni < 4; ++ni) {
        const float a0 = __expf(sc[mi][ni][0] * 0.125f);
        const float a1 = __expf(sc[mi][ni][1] * 0.125f);
        const float a2 = __expf(sc[mi][ni][2] * 0.125f);
        const float a3 = __expf(sc[mi][ni][3] * 0.125f);
        rs += (a0 + a1) + (a2 + a3);
        pw[mi][ni][0] = cvtpk(a0, a1);
        pw[mi][ni][1] = cvtpk(a2, a3);
      }
      rs += __shfl_xor(rs, 16);
      rs += __shfl_xor(rs, 32);
      l_r[mi] += rs;
    }
    // O += P V
    #pragma unroll
    for (int ks = 0; ks < 2; ++ks) {
      bf16x8 bv[4];
      #pragma unroll
      for (int nd = 0; nd < 4; ++nd) {
        const int row = nd * 16 + l4;
        const int blk = (ks * 4 + g) ^ (row & 7);
        bv[nd] = *reinterpret_cast<const bf16x8*>(&Vlds[cur][row * 64 + blk * 8]);
      }
      #pragma unroll
      for (int mi = 0; mi < 2; ++mi) {
        const u32x4 aw = {pw[mi][2 * ks][0], pw[mi][2 * ks][1],
                          pw[mi][2 * ks + 1][0], pw[mi][2 * ks + 1][1]};
        const bf16x8 ap = __builtin_bit_cast(bf16x8, aw);
        #pragma unroll
        for (int nd = 0; nd < 4; ++nd)
          acc_o[mi][nd] = __builtin_amdgcn_mfma_f32_16x16x32_bf16(ap, bv[nd],
                                                                  acc_o[mi][nd], 0, 0, 0);
      }
    }
    __syncthreads();
  }
  // epilogue
  float linv[2][4];
  #pragma unroll
  for (int mi = 0; mi < 2; ++mi)
    #pragma unroll
    for (int r = 0; r < 4; ++r) {
      const int src = (lane & 48) + ((lane & 48) >> 2) + r;
      linv[mi][r] = 1.0f / __shfl(l_r[mi], src);
    }
  #pragma unroll
  for (int mi = 0; mi < 2; ++mi)
    #pragma unroll
    for (int nd = 0; nd < 4; ++nd)
      #pragma unroll
      for (int r = 0; r < 4; ++r) {
        const int grow = b * 2048 + q0 + w * 32 + mi * 16 + g * 4 + r;
        const int gcol = h * 64 + nd * 16 + l4;
        Ao[(size_t)grow * 1088 + gcol] = f2bf(acc_o[mi][nd][r] * linv[mi][r]);
      }
}

// ---------------- secondary attention (R=4, scale 1/2), MFMA, one-pass no-max ----------------
// Q_s/K_s read from QKs cols 2048..2175 (ld 2176).
__global__ __launch_bounds__(256, 2)
void k_attn_sec(const u16* __restrict__ QKs, const u16* __restrict__ Vst,
                u16* __restrict__ Ao) {
  __shared__ __attribute__((aligned(16))) u16 KsL[2048 * 4];   // [s][d] 16KB
  __shared__ __attribute__((aligned(16))) u16 VtL[5 * 2056];   // rows d0..3 + ones, pad 8
  __shared__ __attribute__((aligned(16))) u16 Plds[4][32 * 64];
  const int t = threadIdx.x, w = t >> 6;
  const int lane = t & 63, l4 = lane & 15, g = lane >> 4;
  const int q0 = blockIdx.x * 128, h = blockIdx.y, b = blockIdx.z;

  const u16* Vsrc = Vst + (size_t)((b * 16 + h) * 4) * 2048;
  #pragma unroll
  for (int r = 0; r < 4; ++r)
    gld_lds16(Vsrc + (size_t)r * 2048 + t * 8, &VtL[r * 2056 + w * 512]);
  {
    u16x8 ones;
    #pragma unroll
    for (int j = 0; j < 8; ++j) ones[j] = 0x3F80;
    *reinterpret_cast<u16x8*>(&VtL[4 * 2056 + t * 8]) = ones;
  }
  #pragma unroll
  for (int i = 0; i < 8; ++i) {
    const int s = i * 256 + t;
    const uint2 kk = *reinterpret_cast<const uint2*>(
        QKs + (size_t)(b * 2048 + s) * 2176 + 2112 + h * 4);
    *reinterpret_cast<uint2*>(&KsL[s * 4]) = kk;
  }
  bf16x8 aq[2];
  #pragma unroll
  for (int mi = 0; mi < 2; ++mi) {
    u16x8 qv = {0, 0, 0, 0, 0, 0, 0, 0};
    if (g == 0) {
      const uint2 qq = *reinterpret_cast<const uint2*>(
          QKs + (size_t)(b * 2048 + q0 + w * 32 + mi * 16 + l4) * 2176 + 2048 + h * 4);
      qv[0] = (u16)(qq.x & 0xffff); qv[1] = (u16)(qq.x >> 16);
      qv[2] = (u16)(qq.y & 0xffff); qv[3] = (u16)(qq.y >> 16);
    }
    aq[mi] = __builtin_bit_cast(bf16x8, qv);
  }
  __syncthreads();

  const f32x4 vz = {0.f, 0.f, 0.f, 0.f};
  f32x4 acc[2];
  acc[0] = vz; acc[1] = vz;

  for (int kt = 0; kt < 32; ++kt) {
    f32x4 sc[2][4];
    bf16x8 bk[4];
    #pragma unroll
    for (int ni = 0; ni < 4; ++ni) {
      u16x8 kv = {0, 0, 0, 0, 0, 0, 0, 0};
      if (g == 0) {
        const uint2 kk = *reinterpret_cast<const uint2*>(
            &KsL[(kt * 64 + ni * 16 + l4) * 4]);
        kv[0] = (u16)(kk.x & 0xffff); kv[1] = (u16)(kk.x >> 16);
        kv[2] = (u16)(kk.y & 0xffff); kv[3] = (u16)(kk.y >> 16);
      }
      bk[ni] = __builtin_bit_cast(bf16x8, kv);
    }
    #pragma unroll
    for (int mi = 0; mi < 2; ++mi)
      #pragma unroll
      for (int ni = 0; ni < 4; ++ni)
        sc[mi][ni] = __builtin_amdgcn_mfma_f32_16x16x32_bf16(aq[mi], bk[ni], vz, 0, 0, 0);
    #pragma unroll
    for (int mi = 0; mi < 2; ++mi)
      #pragma unroll
      for (int r = 0; r < 4; ++r) {
        const int prow = mi * 16 + g * 4 + r;
        #pragma unroll
        for (int ni = 0; ni < 4; ++ni) {
          const float p = __expf(sc[mi][ni][r] * 0.5f);
          const int col = ni * 16 + l4;
          Plds[w][prow * 64 + ((col >> 3) ^ (prow & 7)) * 8 + (col & 7)] = f2bf(p);
        }
      }
    asm volatile("s_waitcnt lgkmcnt(0)" ::: "memory");
    #pragma unroll
    for (int ks = 0; ks < 2; ++ks) {
      const int blko = kt * 8 + ks * 4 + g;
      const int vrow = (l4 < 4) ? l4 : 4;
      const bf16x8 bv = *reinterpret_cast<const bf16x8*>(&VtL[vrow * 2056 + blko * 8]);
      #pragma unroll
      for (int mi = 0; mi < 2; ++mi) {
        const int row = mi * 16 + l4;
        const int blk = (ks * 4 + g) ^ (row & 7);
        const bf16x8 ap = *reinterpret_cast<const bf16x8*>(&Plds[w][row * 64 + blk * 8]);
        acc[mi] = __builtin_amdgcn_mfma_f32_16x16x32_bf16(ap, bv, acc[mi], 0, 0, 0);
      }
    }
  }
  #pragma unroll
  for (int mi = 0; mi < 2; ++mi)
    #pragma unroll
    for (int r = 0; r < 4; ++r) {
      const float lsum = __shfl(acc[mi][r], (lane & 48) + 4);
      if (l4 < 4) {
        const int grow = b * 2048 + q0 + w * 32 + mi * 16 + g * 4 + r;
        Ao[(size_t)grow * 1088 + 1024 + h * 4 + l4] = f2bf(acc[mi][r] / lsum);
      }
    }
}

// ---------------- launch ----------------
extern "C" void kernel_launch(void* const* d_in, const int* in_sizes, int n_in,
                              void* d_out, int out_size, void* d_ws, size_t ws_size,
                              hipStream_t stream) {
  (void)in_sizes; (void)n_in; (void)out_size; (void)ws_size;
  const float* x    = (const float*)d_in[0];
  const float* wq_p = (const float*)d_in[1];
  const float* bq_p = (const float*)d_in[2];
  const float* wk_p = (const float*)d_in[3];
  const float* bk_p = (const float*)d_in[4];
  const float* wv_p = (const float*)d_in[5];
  const float* bv_p = (const float*)d_in[6];
  const float* wo_p = (const float*)d_in[7];
  const float* bo_p = (const float*)d_in[8];
  const float* wq_s = (const float*)d_in[9];
  const float* bq_s = (const float*)d_in[10];
  const float* wk_s = (const float*)d_in[11];
  const float* bk_s = (const float*)d_in[12];
  const float* wv_s = (const float*)d_in[13];
  const float* bv_s = (const float*)d_in[14];
  const float* wo_s = (const float*)d_in[15];
  const float* bo_s = (const float*)d_in[16];
  const float* wcr  = (const float*)d_in[17];

  char* p = (char*)d_ws;
  auto take = [&](size_t bytes) { char* r = p; p += (bytes + 255) & ~(size_t)255; return r; };
  u16* xb      = (u16*)take((size_t)4096 * 1024 * 2);
  u16* Wall    = (u16*)take((size_t)2176 * 1024 * 2);   // [Wq_p|Wk_p|wq_s|wk_s]
  u16* Wvt     = (u16*)take((size_t)1024 * 1024 * 2);
  u16* Wvst    = (u16*)take((size_t)64 * 1024 * 2);
  u16* Bto     = (u16*)take((size_t)1024 * 1088 * 2);
  float* ballqk= (float*)take(2176 * 4);
  float* bfin  = (float*)take(1024 * 4);
  u16* QKs     = (u16*)take((size_t)4096 * 2176 * 2);
  u16* Vpt     = (u16*)take((size_t)4096 * 1024 * 2);
  u16* Vst     = (u16*)take((size_t)2 * 16 * 4 * 2048 * 2);
  u16* Ao      = (u16*)take((size_t)4096 * 1088 * 2);

  k_prep<<<6409, 256, 0, stream>>>(x, wq_p, wk_p, wv_p, wo_p, wq_s, wk_s, wv_s, wo_s,
                                   bq_p, bk_p, bq_s, bk_s, bo_p, bo_s, wcr,
                                   xb, Wall, Wvt, Wvst, Bto, ballqk, bfin);

  // fused Q|K|q_s|k_s projection: one contiguous OUTMODE=0 GEMM, N=2176 (=17*128)
  k_gemm_bt<128, 2, 0><<<dim3(32, 17), 256, 0, stream>>>(xb, 1024, Wall, 1024, ballqk,
                                                         QKs, 2176, 1024);
  k_gemm_bt<128, 2, 1, 64><<<dim3(32, 8), 256, 0, stream>>>(xb, 1024, Wvt, 1024, bv_p, Vpt, 0, 1024);
  k_gemm_bt<64, 4, 1, 4><<<dim3(32, 1), 256, 0, stream>>>(xb, 1024, Wvst, 1024, bv_s, Vst, 0, 1024);

  k_attn_primary<<<512, 256, 0, stream>>>(QKs, Vpt, Ao);
  k_attn_sec<<<dim3(16, 16, 2), 256, 0, stream>>>(QKs, Vst, Ao);

  k_gemm_bt<128, 2, 2><<<dim3(32, 8), 256, 0, stream>>>(Ao, 1088, Bto, 1088, bfin, d_out, 1024, 1088);
}

// Round 13
// 188.328 us; speedup vs baseline: 1.1822x; 1.0666x over previous
//
#include <hip/hip_runtime.h>
#include <stdint.h>

typedef unsigned short u16;
typedef __bf16 bf16x8 __attribute__((ext_vector_type(8)));
typedef float f32x4 __attribute__((ext_vector_type(4)));
typedef u16 u16x8 __attribute__((ext_vector_type(8)));
typedef u16 u16x4 __attribute__((ext_vector_type(4)));
typedef unsigned u32x4 __attribute__((ext_vector_type(4)));

// B=2, S=2048, D=1024, H=16, HD=64, R=4. MS = B*S = 4096.
// QKs layout: [4096][2176] = [Q_p (1024) | K_p (1024) | q_s (64) | k_s (64)]

__device__ __forceinline__ u16 f2bf(float f) {
  unsigned u = __builtin_bit_cast(unsigned, f);
  u += 0x7FFFu + ((u >> 16) & 1u);          // RNE
  return (u16)(u >> 16);
}
__device__ __forceinline__ unsigned cvtpk(float lo, float hi) {
  unsigned r;
  asm("v_cvt_pk_bf16_f32 %0, %1, %2" : "=v"(r) : "v"(lo), "v"(hi));
  return r;
}
__device__ __forceinline__ void gld_lds16(const void* g, void* l) {
  __builtin_amdgcn_global_load_lds((__attribute__((address_space(1))) void*)(g),
                                   (__attribute__((address_space(3))) void*)(l),
                                   16, 0, 0);
}

// ---------------- fused prep: conv_x | 4 big transposes | 4 small transposes | bias ------
// grid 6409 x 256: [0,2048) conv_x, [2048,6144) tr_big, [6144,6400) tr_small, [6400,6409) bias
__global__ __launch_bounds__(256)
void k_prep(const float* __restrict__ x,
            const float* __restrict__ wq_p, const float* __restrict__ wk_p,
            const float* __restrict__ wv_p, const float* __restrict__ wo_p,
            const float* __restrict__ wq_s, const float* __restrict__ wk_s,
            const float* __restrict__ wv_s, const float* __restrict__ wo_s,
            const float* __restrict__ bq_p, const float* __restrict__ bk_p,
            const float* __restrict__ bq_s, const float* __restrict__ bk_s,
            const float* __restrict__ bo_p, const float* __restrict__ bo_s,
            const float* __restrict__ wcr,
            u16* __restrict__ xb, u16* __restrict__ Wall, u16* __restrict__ Wvt,
            u16* __restrict__ Wvst, u16* __restrict__ Bto,
            float* __restrict__ ballqk, float* __restrict__ bfin) {
  const int id = blockIdx.x;
  if (id < 2048) {                     // ---- x -> bf16 (proven k_conv_x body)
    const int i = id * 256 + threadIdx.x;
    const float4* p = reinterpret_cast<const float4*>(x) + (size_t)i * 2;
    float4 a = p[0], b = p[1];
    u16x8 o;
    o[0] = f2bf(a.x); o[1] = f2bf(a.y); o[2] = f2bf(a.z); o[3] = f2bf(a.w);
    o[4] = f2bf(b.x); o[5] = f2bf(b.y); o[6] = f2bf(b.z); o[7] = f2bf(b.w);
    *reinterpret_cast<u16x8*>(xb + (size_t)i * 8) = o;
    return;
  }
  if (id < 6400) {                     // ---- transposes (proven tile body)
    __shared__ float tile[32][33];
    const int tx = threadIdx.x & 31, ty = threadIdx.x >> 5;  // 32x8
    const float* src; u16* dst; int N, ldd, n0, k0; float sc = 1.f;
    if (id < 6144) {                   // big: 4 jobs x 1024 tiles (N=1024)
      const int tid = id - 2048, job = tid >> 10, t10 = tid & 1023;
      switch (job) {
        case 0: src = wq_p; dst = Wall;                       ldd = 1024; break;
        case 1: src = wk_p; dst = Wall + (size_t)1024 * 1024; ldd = 1024; break;
        case 2: src = wv_p; dst = Wvt;                        ldd = 1024; break;
        default: src = wo_p; dst = Bto;                       ldd = 1088; break;
      }
      N = 1024; n0 = (t10 & 31) * 32; k0 = (t10 >> 5) * 32;
    } else {                           // small: 4 jobs x 64 tiles
      const int tid = id - 6144, job = tid >> 6, t6 = tid & 63;
      int ntx;
      switch (job) {
        case 0: src = wq_s; dst = Wall + (size_t)2048 * 1024; N = 64;   ldd = 1024; ntx = 2; break;
        case 1: src = wk_s; dst = Wall + (size_t)2112 * 1024; N = 64;   ldd = 1024; ntx = 2; break;
        case 2: src = wv_s; dst = Wvst;                       N = 64;   ldd = 1024; ntx = 2; break;
        default: src = wo_s; dst = Bto + 1024;                N = 1024; ldd = 1088; ntx = 32; sc = wcr[0]; break;
      }
      n0 = (t6 % ntx) * 32; k0 = (t6 / ntx) * 32;
    }
    #pragma unroll
    for (int i = 0; i < 4; ++i)
      tile[ty + i * 8][tx] = src[(size_t)(k0 + ty + i * 8) * N + n0 + tx];
    __syncthreads();
    #pragma unroll
    for (int i = 0; i < 4; ++i)
      dst[(size_t)(n0 + ty + i * 8) * ldd + k0 + tx] = f2bf(tile[tx][ty + i * 8] * sc);
    return;
  }
  // ---- bias prep (proven body)
  const int i = (id - 6400) * 256 + threadIdx.x;
  if (i < 1024)       ballqk[i] = bq_p[i];
  else if (i < 2048)  ballqk[i] = bk_p[i - 1024];
  else if (i < 2112)  ballqk[i] = bq_s[i - 2048];
  else if (i < 2176)  ballqk[i] = bk_s[i - 2112];
  if (i < 1024) bfin[i] = bo_p[i] + wcr[0] * bo_s[i];
}

// ---------------- GEMM: C[M=4096][N] = A[M][K]bf16 @ Bt[N][K]bf16^T + bias ----------------
// BM=128, BK=32, double-buffered single-barrier k-loop.
// OUTMODE: 0 = bf16 [row][ldc], 1 = bf16 transposed [b][h][d][s] (head dim OHD), 2 = fp32.
template <int BN, int WAVES_M, int OUTMODE, int OHD = 64>
__global__ __launch_bounds__(256, 2)
void k_gemm_bt(const u16* __restrict__ A, int lda,
               const u16* __restrict__ Bt, int ldb,
               const float* __restrict__ bias,
               void* __restrict__ Cv, int ldc, int K) {
  constexpr int WM = 128 / WAVES_M;
  constexpr int MF = WM / 16;
  __shared__ __attribute__((aligned(16))) u16 Atile[2][128 * 32];
  __shared__ __attribute__((aligned(16))) u16 Btile[2][BN * 32];
  const int t = threadIdx.x, w = t >> 6;
  const int lane = t & 63, l4 = lane & 15, g = lane >> 4;
  const int wr = (WAVES_M == 4) ? w : (w >> 1);
  const int wc = (WAVES_M == 4) ? 0 : (w & 1);
  const int m0 = blockIdx.x * 128, n0 = blockIdx.y * BN;

  auto stage = [&](int buf, int kt) {
    const int k0 = kt * 32;
    #pragma unroll
    for (int r = 0; r < 2; ++r) {
      const int slot = r * 256 + t;
      const int row = slot >> 2, blk = slot & 3;
      const int srcb = blk ^ ((row >> 1) & 3);
      gld_lds16(A + (size_t)(m0 + row) * lda + k0 + srcb * 8,
                &Atile[buf][(r * 256 + w * 64) * 8]);
    }
    #pragma unroll
    for (int r = 0; r < BN / 64; ++r) {
      const int slot = r * 256 + t;
      const int row = slot >> 2, blk = slot & 3;
      const int srcb = blk ^ ((row >> 1) & 3);
      gld_lds16(Bt + (size_t)(n0 + row) * ldb + k0 + srcb * 8,
                &Btile[buf][(r * 256 + w * 64) * 8]);
    }
  };

  const f32x4 vz = {0.f, 0.f, 0.f, 0.f};
  f32x4 acc[MF][4];
  #pragma unroll
  for (int mi = 0; mi < MF; ++mi)
    #pragma unroll
    for (int ni = 0; ni < 4; ++ni) acc[mi][ni] = vz;

  const int nkt = K >> 5;
  stage(0, 0);
  __syncthreads();
  for (int kt = 0; kt < nkt; ++kt) {
    const int cur = kt & 1;
    if (kt + 1 < nkt) stage(cur ^ 1, kt + 1);   // prefetch overlaps compute below
    bf16x8 af[MF], bfv[4];
    #pragma unroll
    for (int mi = 0; mi < MF; ++mi) {
      const int row = wr * WM + mi * 16 + l4;
      const int blk = g ^ ((row >> 1) & 3);
      af[mi] = *reinterpret_cast<const bf16x8*>(&Atile[cur][row * 32 + blk * 8]);
    }
    #pragma unroll
    for (int ni = 0; ni < 4; ++ni) {
      const int row = wc * 64 + ni * 16 + l4;
      const int blk = g ^ ((row >> 1) & 3);
      bfv[ni] = *reinterpret_cast<const bf16x8*>(&Btile[cur][row * 32 + blk * 8]);
    }
    #pragma unroll
    for (int mi = 0; mi < MF; ++mi)
      #pragma unroll
      for (int ni = 0; ni < 4; ++ni)
        acc[mi][ni] = __builtin_amdgcn_mfma_f32_16x16x32_bf16(af[mi], bfv[ni],
                                                              acc[mi][ni], 0, 0, 0);
    __syncthreads();   // drains prefetch + all waves done with buf[cur]
  }
  // epilogue. C/D layout: col = lane&15, row = (lane>>4)*4 + reg
  #pragma unroll
  for (int mi = 0; mi < MF; ++mi) {
    #pragma unroll
    for (int ni = 0; ni < 4; ++ni) {
      const int grow0 = m0 + wr * WM + mi * 16 + g * 4;
      const int gcol = n0 + wc * 64 + ni * 16 + l4;
      const float bb = bias ? bias[gcol] : 0.f;
      if constexpr (OUTMODE == 1) {
        const int bidx = grow0 >> 11, s0 = grow0 & 2047;
        const int hh = gcol / OHD, dd = gcol % OHD;
        u16x4 ov;
        #pragma unroll
        for (int r = 0; r < 4; ++r) ov[r] = f2bf(acc[mi][ni][r] + bb);
        *reinterpret_cast<u16x4*>((u16*)Cv +
            (size_t)((bidx * 16 + hh) * OHD + dd) * 2048 + s0) = ov;
      } else {
        #pragma unroll
        for (int r = 0; r < 4; ++r) {
          const float v = acc[mi][ni][r] + bb;
          if constexpr (OUTMODE == 0)
            ((u16*)Cv)[(size_t)(grow0 + r) * ldc + gcol] = f2bf(v);
          else
            ((float*)Cv)[(size_t)(grow0 + r) * ldc + gcol] = v;
        }
      }
    }
  }
}

// ---------------- fused attention: [0,512) primary | [512,1024) secondary ----------------
// Bodies are the R12-proven kernels verbatim; LDS aliased via one carve (branch is
// block-uniform). Primary adds T5 s_setprio around its MFMA clusters (attn-proven +4-7%).
__global__ __launch_bounds__(256, 2)
void k_attn(const u16* __restrict__ QKs, const u16* __restrict__ Vpt,
            const u16* __restrict__ Vst, u16* __restrict__ Ao) {
  __shared__ __attribute__((aligned(16))) u16 sm[26664];  // 53.3KB union
  const int t = threadIdx.x, w = t >> 6;
  const int lane = t & 63, l4 = lane & 15, g = lane >> 4;

  if (blockIdx.x < 512) {
    // ================= primary (R12 body; LDS: Klds=sm[0..8191], Vlds=sm[8192..16383])
    u16* Klds = sm;          // [2][4096]
    u16* Vlds = sm + 8192;   // [2][4096]
    const int id = blockIdx.x;
    const int lin = (id & 7) * 64 + (id >> 3);
    const int qt = lin & 15, hb = lin >> 4;
    const int h = hb & 15, b = hb >> 4;
    const int q0 = qt * 128;

    const u16* Qbase = QKs + (size_t)(b * 2048 + q0) * 2176 + h * 64;
    const u16* Kbase = QKs + (size_t)(b * 2048) * 2176 + 1024 + h * 64;
    const u16* Vbase = Vpt + (size_t)((b * 16 + h) * 64) * 2048;

    #pragma unroll
    for (int r = 0; r < 2; ++r) {  // K (row-permuted), V tile 0 -> buf 0
      const int sl = r * 256 + t, row = sl >> 3, blk = sl & 7;
      const int srcb = blk ^ (row & 7);
      const int prow = (row & 32) | (((row >> 2) & 3) << 3) | (((row >> 4) & 1) << 2) | (row & 3);
      gld_lds16(Kbase + (size_t)prow * 2176 + srcb * 8, &Klds[(r * 256 + w * 64) * 8]);
      gld_lds16(Vbase + (size_t)row * 2048 + srcb * 8, &Vlds[(r * 256 + w * 64) * 8]);
    }

    bf16x8 aq[2][2];
    #pragma unroll
    for (int mi = 0; mi < 2; ++mi)
      #pragma unroll
      for (int kd = 0; kd < 2; ++kd)
        aq[mi][kd] = *reinterpret_cast<const bf16x8*>(
            Qbase + (size_t)(w * 32 + mi * 16 + l4) * 2176 + kd * 32 + g * 8);

    __syncthreads();

    const f32x4 vz = {0.f, 0.f, 0.f, 0.f};
    float l_r[2] = {0.f, 0.f};
    f32x4 acc_o[2][4];
    #pragma unroll
    for (int mi = 0; mi < 2; ++mi)
      #pragma unroll
      for (int nd = 0; nd < 4; ++nd) acc_o[mi][nd] = vz;

    for (int kt = 0; kt < 32; ++kt) {
      const int cur = kt & 1;
      if (kt < 31) {
        const int kn = kt + 1;
        #pragma unroll
        for (int r = 0; r < 2; ++r) {
          const int sl = r * 256 + t, row = sl >> 3, blk = sl & 7;
          const int srcb = blk ^ (row & 7);
          const int prow = (row & 32) | (((row >> 2) & 3) << 3) | (((row >> 4) & 1) << 2) | (row & 3);
          gld_lds16(Kbase + (size_t)(kn * 64 + prow) * 2176 + srcb * 8,
                    &Klds[(cur ^ 1) * 4096 + (r * 256 + w * 64) * 8]);
          gld_lds16(Vbase + (size_t)row * 2048 + kn * 64 + srcb * 8,
                    &Vlds[(cur ^ 1) * 4096 + (r * 256 + w * 64) * 8]);
        }
      }
      // S^T = mfma(K_frag, Q_frag)
      f32x4 sc[2][4];
      #pragma unroll
      for (int mi = 0; mi < 2; ++mi)
        #pragma unroll
        for (int ni = 0; ni < 4; ++ni) sc[mi][ni] = vz;
      #pragma unroll
      for (int kd = 0; kd < 2; ++kd) {
        bf16x8 bk[4];
        #pragma unroll
        for (int ni = 0; ni < 4; ++ni) {
          const int row = ni * 16 + l4;
          const int blk = (kd * 4 + g) ^ (row & 7);
          bk[ni] = *reinterpret_cast<const bf16x8*>(&Klds[cur * 4096 + row * 64 + blk * 8]);
        }
        __builtin_amdgcn_s_setprio(1);
        #pragma unroll
        for (int mi = 0; mi < 2; ++mi)
          #pragma unroll
          for (int ni = 0; ni < 4; ++ni)
            sc[mi][ni] = __builtin_amdgcn_mfma_f32_16x16x32_bf16(bk[ni], aq[mi][kd],
                                                                 sc[mi][ni], 0, 0, 0);
        __builtin_amdgcn_s_setprio(0);
      }
      // in-register softmax
      unsigned pw[2][4][2];
      #pragma unroll
      for (int mi = 0; mi < 2; ++mi) {
        float rs = 0.f;
        #pragma unroll
        for (int ni = 0; ni < 4; ++ni) {
          const float a0 = __expf(sc[mi][ni][0] * 0.125f);
          const float a1 = __expf(sc[mi][ni][1] * 0.125f);
          const float a2 = __expf(sc[mi][ni][2] * 0.125f);
          const float a3 = __expf(sc[mi][ni][3] * 0.125f);
          rs += (a0 + a1) + (a2 + a3);
          pw[mi][ni][0] = cvtpk(a0, a1);
          pw[mi][ni][1] = cvtpk(a2, a3);
        }
        rs += __shfl_xor(rs, 16);
        rs += __shfl_xor(rs, 32);
        l_r[mi] += rs;
      }
      // O += P V
      #pragma unroll
      for (int ks = 0; ks < 2; ++ks) {
        bf16x8 bv[4];
        #pragma unroll
        for (int nd = 0; nd < 4; ++nd) {
          const int row = nd * 16 + l4;
          const int blk = (ks * 4 + g) ^ (row & 7);
          bv[nd] = *reinterpret_cast<const bf16x8*>(&Vlds[cur * 4096 + row * 64 + blk * 8]);
        }
        __builtin_amdgcn_s_setprio(1);
        #pragma unroll
        for (int mi = 0; mi < 2; ++mi) {
          const u32x4 aw = {pw[mi][2 * ks][0], pw[mi][2 * ks][1],
                            pw[mi][2 * ks + 1][0], pw[mi][2 * ks + 1][1]};
          const bf16x8 ap = __builtin_bit_cast(bf16x8, aw);
          #pragma unroll
          for (int nd = 0; nd < 4; ++nd)
            acc_o[mi][nd] = __builtin_amdgcn_mfma_f32_16x16x32_bf16(ap, bv[nd],
                                                                    acc_o[mi][nd], 0, 0, 0);
        }
        __builtin_amdgcn_s_setprio(0);
      }
      __syncthreads();
    }
    // epilogue
    float linv[2][4];
    #pragma unroll
    for (int mi = 0; mi < 2; ++mi)
      #pragma unroll
      for (int r = 0; r < 4; ++r) {
        const int src = (lane & 48) + ((lane & 48) >> 2) + r;
        linv[mi][r] = 1.0f / __shfl(l_r[mi], src);
      }
    #pragma unroll
    for (int mi = 0; mi < 2; ++mi)
      #pragma unroll
      for (int nd = 0; nd < 4; ++nd)
        #pragma unroll
        for (int r = 0; r < 4; ++r) {
          const int grow = b * 2048 + q0 + w * 32 + mi * 16 + g * 4 + r;
          const int gcol = h * 64 + nd * 16 + l4;
          Ao[(size_t)grow * 1088 + gcol] = f2bf(acc_o[mi][nd][r] * linv[mi][r]);
        }
    return;
  }

  // ================= secondary (R12 body; LDS: KsL=sm[0..8191], VtL=sm[8192..18471],
  // Plds=sm[18472..26663])
  u16* KsL = sm;             // [2048*4]
  u16* VtL = sm + 8192;      // [5*2056]
  u16* Plds = sm + 18472;    // [4][2048]
  const int sid = blockIdx.x - 512;
  const int q0 = (sid & 15) * 128, h = (sid >> 4) & 15, b = sid >> 8;

  const u16* Vsrc = Vst + (size_t)((b * 16 + h) * 4) * 2048;
  #pragma unroll
  for (int r = 0; r < 4; ++r)
    gld_lds16(Vsrc + (size_t)r * 2048 + t * 8, &VtL[r * 2056 + w * 512]);
  {
    u16x8 ones;
    #pragma unroll
    for (int j = 0; j < 8; ++j) ones[j] = 0x3F80;
    *reinterpret_cast<u16x8*>(&VtL[4 * 2056 + t * 8]) = ones;
  }
  #pragma unroll
  for (int i = 0; i < 8; ++i) {
    const int s = i * 256 + t;
    const uint2 kk = *reinterpret_cast<const uint2*>(
        QKs + (size_t)(b * 2048 + s) * 2176 + 2112 + h * 4);
    *reinterpret_cast<uint2*>(&KsL[s * 4]) = kk;
  }
  bf16x8 aq[2];
  #pragma unroll
  for (int mi = 0; mi < 2; ++mi) {
    u16x8 qv = {0, 0, 0, 0, 0, 0, 0, 0};
    if (g == 0) {
      const uint2 qq = *reinterpret_cast<const uint2*>(
          QKs + (size_t)(b * 2048 + q0 + w * 32 + mi * 16 + l4) * 2176 + 2048 + h * 4);
      qv[0] = (u16)(qq.x & 0xffff); qv[1] = (u16)(qq.x >> 16);
      qv[2] = (u16)(qq.y & 0xffff); qv[3] = (u16)(qq.y >> 16);
    }
    aq[mi] = __builtin_bit_cast(bf16x8, qv);
  }
  __syncthreads();

  const f32x4 vz = {0.f, 0.f, 0.f, 0.f};
  f32x4 acc[2];
  acc[0] = vz; acc[1] = vz;

  for (int kt = 0; kt < 32; ++kt) {
    f32x4 sc[2][4];
    bf16x8 bk[4];
    #pragma unroll
    for (int ni = 0; ni < 4; ++ni) {
      u16x8 kv = {0, 0, 0, 0, 0, 0, 0, 0};
      if (g == 0) {
        const uint2 kk = *reinterpret_cast<const uint2*>(
            &KsL[(kt * 64 + ni * 16 + l4) * 4]);
        kv[0] = (u16)(kk.x & 0xffff); kv[1] = (u16)(kk.x >> 16);
        kv[2] = (u16)(kk.y & 0xffff); kv[3] = (u16)(kk.y >> 16);
      }
      bk[ni] = __builtin_bit_cast(bf16x8, kv);
    }
    #pragma unroll
    for (int mi = 0; mi < 2; ++mi)
      #pragma unroll
      for (int ni = 0; ni < 4; ++ni)
        sc[mi][ni] = __builtin_amdgcn_mfma_f32_16x16x32_bf16(aq[mi], bk[ni], vz, 0, 0, 0);
    #pragma unroll
    for (int mi = 0; mi < 2; ++mi)
      #pragma unroll
      for (int r = 0; r < 4; ++r) {
        const int prow = mi * 16 + g * 4 + r;
        #pragma unroll
        for (int ni = 0; ni < 4; ++ni) {
          const float p = __expf(sc[mi][ni][r] * 0.5f);
          const int col = ni * 16 + l4;
          Plds[w * 2048 + prow * 64 + ((col >> 3) ^ (prow & 7)) * 8 + (col & 7)] = f2bf(p);
        }
      }
  asm volatile("s_waitcnt lgkmcnt(0)" ::: "memory");
    #pragma unroll
    for (int ks = 0; ks < 2; ++ks) {
      const int blko = kt * 8 + ks * 4 + g;
      const int vrow = (l4 < 4) ? l4 : 4;
      const bf16x8 bv = *reinterpret_cast<const bf16x8*>(&VtL[vrow * 2056 + blko * 8]);
      #pragma unroll
      for (int mi = 0; mi < 2; ++mi) {
        const int row = mi * 16 + l4;
        const int blk = (ks * 4 + g) ^ (row & 7);
        const bf16x8 ap = *reinterpret_cast<const bf16x8*>(&Plds[w * 2048 + row * 64 + blk * 8]);
        acc[mi] = __builtin_amdgcn_mfma_f32_16x16x32_bf16(ap, bv, acc[mi], 0, 0, 0);
      }
    }
  }
  #pragma unroll
  for (int mi = 0; mi < 2; ++mi)
    #pragma unroll
    for (int r = 0; r < 4; ++r) {
      const float lsum = __shfl(acc[mi][r], (lane & 48) + 4);
      if (l4 < 4) {
        const int grow = b * 2048 + q0 + w * 32 + mi * 16 + g * 4 + r;
        Ao[(size_t)grow * 1088 + 1024 + h * 4 + l4] = f2bf(acc[mi][r] / lsum);
      }
    }
}

// ---------------- launch ----------------
extern "C" void kernel_launch(void* const* d_in, const int* in_sizes, int n_in,
                              void* d_out, int out_size, void* d_ws, size_t ws_size,
                              hipStream_t stream) {
  (void)in_sizes; (void)n_in; (void)out_size; (void)ws_size;
  const float* x    = (const float*)d_in[0];
  const float* wq_p = (const float*)d_in[1];
  const float* bq_p = (const float*)d_in[2];
  const float* wk_p = (const float*)d_in[3];
  const float* bk_p = (const float*)d_in[4];
  const float* wv_p = (const float*)d_in[5];
  const float* bv_p = (const float*)d_in[6];
  const float* wo_p = (const float*)d_in[7];
  const float* bo_p = (const float*)d_in[8];
  const float* wq_s = (const float*)d_in[9];
  const float* bq_s = (const float*)d_in[10];
  const float* wk_s = (const float*)d_in[11];
  const float* bk_s = (const float*)d_in[12];
  const float* wv_s = (const float*)d_in[13];
  const float* bv_s = (const float*)d_in[14];
  const float* wo_s = (const float*)d_in[15];
  const float* bo_s = (const float*)d_in[16];
  const float* wcr  = (const float*)d_in[17];

  char* p = (char*)d_ws;
  auto take = [&](size_t bytes) { char* r = p; p += (bytes + 255) & ~(size_t)255; return r; };
  u16* xb      = (u16*)take((size_t)4096 * 1024 * 2);
  u16* Wall    = (u16*)take((size_t)2176 * 1024 * 2);   // [Wq_p|Wk_p|wq_s|wk_s]
  u16* Wvt     = (u16*)take((size_t)1024 * 1024 * 2);
  u16* Wvst    = (u16*)take((size_t)64 * 1024 * 2);
  u16* Bto     = (u16*)take((size_t)1024 * 1088 * 2);
  float* ballqk= (float*)take(2176 * 4);
  float* bfin  = (float*)take(1024 * 4);
  u16* QKs     = (u16*)take((size_t)4096 * 2176 * 2);
  u16* Vpt     = (u16*)take((size_t)4096 * 1024 * 2);
  u16* Vst     = (u16*)take((size_t)2 * 16 * 4 * 2048 * 2);
  u16* Ao      = (u16*)take((size_t)4096 * 1088 * 2);

  k_prep<<<6409, 256, 0, stream>>>(x, wq_p, wk_p, wv_p, wo_p, wq_s, wk_s, wv_s, wo_s,
                                   bq_p, bk_p, bq_s, bk_s, bo_p, bo_s, wcr,
                                   xb, Wall, Wvt, Wvst, Bto, ballqk, bfin);

  // fused Q|K|q_s|k_s projection: one contiguous OUTMODE=0 GEMM, N=2176 (=17*128)
  k_gemm_bt<128, 2, 0><<<dim3(32, 17), 256, 0, stream>>>(xb, 1024, Wall, 1024, ballqk,
                                                         QKs, 2176, 1024);
  k_gemm_bt<128, 2, 1, 64><<<dim3(32, 8), 256, 0, stream>>>(xb, 1024, Wvt, 1024, bv_p, Vpt, 0, 1024);
  k_gemm_bt<64, 4, 1, 4><<<dim3(32, 1), 256, 0, stream>>>(xb, 1024, Wvst, 1024, bv_s, Vst, 0, 1024);

  k_attn<<<1024, 256, 0, stream>>>(QKs, Vpt, Vst, Ao);

  k_gemm_bt<128, 2, 2><<<dim3(32, 8), 256, 0, stream>>>(Ao, 1088, Bto, 1088, bfin, d_out, 1024, 1088);
}

// Round 14
// 154.821 us; speedup vs baseline: 1.4381x; 1.2164x over previous
//
#include <hip/hip_runtime.h>
#include <stdint.h>

typedef unsigned short u16;
typedef __bf16 bf16x8 __attribute__((ext_vector_type(8)));
typedef float f32x4 __attribute__((ext_vector_type(4)));
typedef u16 u16x8 __attribute__((ext_vector_type(8)));
typedef u16 u16x4 __attribute__((ext_vector_type(4)));
typedef unsigned u32x4 __attribute__((ext_vector_type(4)));

// B=2, S=2048, D=1024, H=16, HD=64, R=4. MS = B*S = 4096.
// QKs layout: [4096][2176] = [Q_p (1024) | K_p (1024) | q_s (64) | k_s (64)]

__device__ __forceinline__ u16 f2bf(float f) {
  unsigned u = __builtin_bit_cast(unsigned, f);
  u += 0x7FFFu + ((u >> 16) & 1u);          // RNE
  return (u16)(u >> 16);
}
__device__ __forceinline__ unsigned cvtpk(float lo, float hi) {
  unsigned r;
  asm("v_cvt_pk_bf16_f32 %0, %1, %2" : "=v"(r) : "v"(lo), "v"(hi));
  return r;
}
__device__ __forceinline__ void gld_lds16(const void* g, void* l) {
  __builtin_amdgcn_global_load_lds((__attribute__((address_space(1))) void*)(g),
                                   (__attribute__((address_space(3))) void*)(l),
                                   16, 0, 0);
}

// ---------------- fused prep: conv_x | 4 big transposes | 4 small transposes | bias ------
__global__ __launch_bounds__(256)
void k_prep(const float* __restrict__ x,
            const float* __restrict__ wq_p, const float* __restrict__ wk_p,
            const float* __restrict__ wv_p, const float* __restrict__ wo_p,
            const float* __restrict__ wq_s, const float* __restrict__ wk_s,
            const float* __restrict__ wv_s, const float* __restrict__ wo_s,
            const float* __restrict__ bq_p, const float* __restrict__ bk_p,
            const float* __restrict__ bq_s, const float* __restrict__ bk_s,
            const float* __restrict__ bo_p, const float* __restrict__ bo_s,
            const float* __restrict__ wcr,
            u16* __restrict__ xb, u16* __restrict__ Wall, u16* __restrict__ Wvt,
            u16* __restrict__ Wvst, u16* __restrict__ Bto,
            float* __restrict__ ballqk, float* __restrict__ bfin) {
  const int id = blockIdx.x;
  if (id < 2048) {                     // ---- x -> bf16
    const int i = id * 256 + threadIdx.x;
    const float4* p = reinterpret_cast<const float4*>(x) + (size_t)i * 2;
    float4 a = p[0], b = p[1];
    u16x8 o;
    o[0] = f2bf(a.x); o[1] = f2bf(a.y); o[2] = f2bf(a.z); o[3] = f2bf(a.w);
    o[4] = f2bf(b.x); o[5] = f2bf(b.y); o[6] = f2bf(b.z); o[7] = f2bf(b.w);
    *reinterpret_cast<u16x8*>(xb + (size_t)i * 8) = o;
    return;
  }
  if (id < 6400) {                     // ---- transposes
    __shared__ float tile[32][33];
    const int tx = threadIdx.x & 31, ty = threadIdx.x >> 5;  // 32x8
    const float* src; u16* dst; int N, ldd, n0, k0; float sc = 1.f;
    if (id < 6144) {                   // big: 4 jobs x 1024 tiles (N=1024)
      const int tid = id - 2048, job = tid >> 10, t10 = tid & 1023;
      switch (job) {
        case 0: src = wq_p; dst = Wall;                       ldd = 1024; break;
        case 1: src = wk_p; dst = Wall + (size_t)1024 * 1024; ldd = 1024; break;
        case 2: src = wv_p; dst = Wvt;                        ldd = 1024; break;
        default: src = wo_p; dst = Bto;                       ldd = 1088; break;
      }
      N = 1024; n0 = (t10 & 31) * 32; k0 = (t10 >> 5) * 32;
    } else {                           // small: 4 jobs x 64 tiles
      const int tid = id - 6144, job = tid >> 6, t6 = tid & 63;
      int ntx;
      switch (job) {
        case 0: src = wq_s; dst = Wall + (size_t)2048 * 1024; N = 64;   ldd = 1024; ntx = 2; break;
        case 1: src = wk_s; dst = Wall + (size_t)2112 * 1024; N = 64;   ldd = 1024; ntx = 2; break;
        case 2: src = wv_s; dst = Wvst;                       N = 64;   ldd = 1024; ntx = 2; break;
        default: src = wo_s; dst = Bto + 1024;                N = 1024; ldd = 1088; ntx = 32; sc = wcr[0]; break;
      }
      n0 = (t6 % ntx) * 32; k0 = (t6 / ntx) * 32;
    }
    #pragma unroll
    for (int i = 0; i < 4; ++i)
      tile[ty + i * 8][tx] = src[(size_t)(k0 + ty + i * 8) * N + n0 + tx];
    __syncthreads();
    #pragma unroll
    for (int i = 0; i < 4; ++i)
      dst[(size_t)(n0 + ty + i * 8) * ldd + k0 + tx] = f2bf(tile[tx][ty + i * 8] * sc);
    return;
  }
  // ---- bias prep
  const int i = (id - 6400) * 256 + threadIdx.x;
  if (i < 1024)       ballqk[i] = bq_p[i];
  else if (i < 2048)  ballqk[i] = bk_p[i - 1024];
  else if (i < 2112)  ballqk[i] = bq_s[i - 2048];
  else if (i < 2176)  ballqk[i] = bk_s[i - 2112];
  if (i < 1024) bfin[i] = bo_p[i] + wcr[0] * bo_s[i];
}

// ---------------- GEMM body (device fn over LDS carve) ----------------
// BM=128, BK=32, double-buffered single-barrier k-loop (R12-proven).
// smem carve: Atile = sm[0 .. 2*4096), Btile = sm[8192 .. 8192 + 2*BN*32)
template <int BN, int WAVES_M, int OUTMODE, int OHD>
__device__ __forceinline__
void gemm_body(const u16* __restrict__ A, int lda,
               const u16* __restrict__ Bt, int ldb,
               const float* __restrict__ bias,
               void* __restrict__ Cv, int ldc, int K,
               int bx, int by, u16* sm) {
  constexpr int WM = 128 / WAVES_M;
  constexpr int MF = WM / 16;
  u16* Atile = sm;                 // [2][4096]
  u16* Btile = sm + 8192;          // [2][BN*32]
  const int t = threadIdx.x, w = t >> 6;
  const int lane = t & 63, l4 = lane & 15, g = lane >> 4;
  const int wr = (WAVES_M == 4) ? w : (w >> 1);
  const int wc = (WAVES_M == 4) ? 0 : (w & 1);
  const int m0 = bx * 128, n0 = by * BN;

  auto stage = [&](int buf, int kt) {
    const int k0 = kt * 32;
    #pragma unroll
    for (int r = 0; r < 2; ++r) {
      const int slot = r * 256 + t;
      const int row = slot >> 2, blk = slot & 3;
      const int srcb = blk ^ ((row >> 1) & 3);
      gld_lds16(A + (size_t)(m0 + row) * lda + k0 + srcb * 8,
                &Atile[buf * 4096 + (r * 256 + w * 64) * 8]);
    }
    #pragma unroll
    for (int r = 0; r < BN / 64; ++r) {
      const int slot = r * 256 + t;
      const int row = slot >> 2, blk = slot & 3;
      const int srcb = blk ^ ((row >> 1) & 3);
      gld_lds16(Bt + (size_t)(n0 + row) * ldb + k0 + srcb * 8,
                &Btile[buf * (BN * 32) + (r * 256 + w * 64) * 8]);
    }
  };

  const f32x4 vz = {0.f, 0.f, 0.f, 0.f};
  f32x4 acc[MF][4];
  #pragma unroll
  for (int mi = 0; mi < MF; ++mi)
    #pragma unroll
    for (int ni = 0; ni < 4; ++ni) acc[mi][ni] = vz;

  const int nkt = K >> 5;
  stage(0, 0);
  __syncthreads();
  for (int kt = 0; kt < nkt; ++kt) {
    const int cur = kt & 1;
    if (kt + 1 < nkt) stage(cur ^ 1, kt + 1);   // prefetch overlaps compute below
    bf16x8 af[MF], bfv[4];
    #pragma unroll
    for (int mi = 0; mi < MF; ++mi) {
      const int row = wr * WM + mi * 16 + l4;
      const int blk = g ^ ((row >> 1) & 3);
      af[mi] = *reinterpret_cast<const bf16x8*>(&Atile[cur * 4096 + row * 32 + blk * 8]);
    }
    #pragma unroll
    for (int ni = 0; ni < 4; ++ni) {
      const int row = wc * 64 + ni * 16 + l4;
      const int blk = g ^ ((row >> 1) & 3);
      bfv[ni] = *reinterpret_cast<const bf16x8*>(&Btile[cur * (BN * 32) + row * 32 + blk * 8]);
    }
    #pragma unroll
    for (int mi = 0; mi < MF; ++mi)
      #pragma unroll
      for (int ni = 0; ni < 4; ++ni)
        acc[mi][ni] = __builtin_amdgcn_mfma_f32_16x16x32_bf16(af[mi], bfv[ni],
                                                              acc[mi][ni], 0, 0, 0);
    __syncthreads();
  }
  // epilogue. C/D layout: col = lane&15, row = (lane>>4)*4 + reg
  #pragma unroll
  for (int mi = 0; mi < MF; ++mi) {
    #pragma unroll
    for (int ni = 0; ni < 4; ++ni) {
      const int grow0 = m0 + wr * WM + mi * 16 + g * 4;
      const int gcol = n0 + wc * 64 + ni * 16 + l4;
      const float bb = bias ? bias[gcol] : 0.f;
      if constexpr (OUTMODE == 1) {
        const int bidx = grow0 >> 11, s0 = grow0 & 2047;
        const int hh = gcol / OHD, dd = gcol % OHD;
        u16x4 ov;
        #pragma unroll
        for (int r = 0; r < 4; ++r) ov[r] = f2bf(acc[mi][ni][r] + bb);
        *reinterpret_cast<u16x4*>((u16*)Cv +
            (size_t)((bidx * 16 + hh) * OHD + dd) * 2048 + s0) = ov;
      } else {
        #pragma unroll
        for (int r = 0; r < 4; ++r) {
          const float v = acc[mi][ni][r] + bb;
          if constexpr (OUTMODE == 0)
            ((u16*)Cv)[(size_t)(grow0 + r) * ldc + gcol] = f2bf(v);
          else
            ((float*)Cv)[(size_t)(grow0 + r) * ldc + gcol] = v;
        }
      }
    }
  }
}

// ---------------- fused projections: [0,544) QK | [544,800) V | [800,832) Vst ------------
__global__ __launch_bounds__(256, 2)
void k_proj3(const u16* __restrict__ xb, const u16* __restrict__ Wall,
             const u16* __restrict__ Wvt, const u16* __restrict__ Wvst,
             const float* __restrict__ ballqk, const float* __restrict__ bv_p,
             const float* __restrict__ bv_s,
             u16* __restrict__ QKs, u16* __restrict__ Vpt, u16* __restrict__ Vst) {
  __shared__ __attribute__((aligned(16))) u16 sm[16384];  // 32KB (max of branches)
  const int id = blockIdx.x;
  if (id < 544) {
    gemm_body<128, 2, 0, 64>(xb, 1024, Wall, 1024, ballqk, QKs, 2176, 1024,
                             id & 31, id >> 5, sm);
  } else if (id < 800) {
    const int lid = id - 544;
    gemm_body<128, 2, 1, 64>(xb, 1024, Wvt, 1024, bv_p, Vpt, 0, 1024,
                             lid & 31, lid >> 5, sm);
  } else {
    const int lid = id - 800;
    gemm_body<64, 4, 1, 4>(xb, 1024, Wvst, 1024, bv_s, Vst, 0, 1024,
                           lid & 31, lid >> 5, sm);
  }
}

// ---------------- final GEMM wrapper ----------------
__global__ __launch_bounds__(256, 2)
void k_gemm_final(const u16* __restrict__ A, const u16* __restrict__ Bt,
                  const float* __restrict__ bias, float* __restrict__ C) {
  __shared__ __attribute__((aligned(16))) u16 sm[16384];
  gemm_body<128, 2, 2, 64>(A, 1088, Bt, 1088, bias, C, 1024, 1088,
                           blockIdx.x, blockIdx.y, sm);
}

// ---------------- fused attention, CU-paired interleave ----------------
// Blocks in groups of 8: even group -> primary, odd -> secondary. id%8 preserved for both
// (keeps primary's XCD/L2 grouping). Pairs one MFMA-bound primary with one VALU-bound sec
// per CU's 2 slots -> pipes overlap (m114).
__global__ __launch_bounds__(256, 2)
void k_attn(const u16* __restrict__ QKs, const u16* __restrict__ Vpt,
            const u16* __restrict__ Vst, u16* __restrict__ Ao) {
  __shared__ __attribute__((aligned(16))) u16 sm[26664];  // 53.3KB union
  const int t = threadIdx.x, w = t >> 6;
  const int lane = t & 63, l4 = lane & 15, g = lane >> 4;
  const int grp = blockIdx.x >> 3, sub = blockIdx.x & 7;

  if ((grp & 1) == 0) {
    // ================= primary (R12 body; LDS: Klds=sm[0..8191], Vlds=sm[8192..16383])
    u16* Klds = sm;          // [2][4096]
    u16* Vlds = sm + 8192;   // [2][4096]
    const int id = (grp >> 1) * 8 + sub;      // [0,512)
    const int lin = (id & 7) * 64 + (id >> 3);
    const int qt = lin & 15, hb = lin >> 4;
    const int h = hb & 15, b = hb >> 4;
    const int q0 = qt * 128;

    const u16* Qbase = QKs + (size_t)(b * 2048 + q0) * 2176 + h * 64;
    const u16* Kbase = QKs + (size_t)(b * 2048) * 2176 + 1024 + h * 64;
    const u16* Vbase = Vpt + (size_t)((b * 16 + h) * 64) * 2048;

    #pragma unroll
    for (int r = 0; r < 2; ++r) {  // K (row-permuted), V tile 0 -> buf 0
      const int sl = r * 256 + t, row = sl >> 3, blk = sl & 7;
      const int srcb = blk ^ (row & 7);
      const int prow = (row & 32) | (((row >> 2) & 3) << 3) | (((row >> 4) & 1) << 2) | (row & 3);
      gld_lds16(Kbase + (size_t)prow * 2176 + srcb * 8, &Klds[(r * 256 + w * 64) * 8]);
      gld_lds16(Vbase + (size_t)row * 2048 + srcb * 8, &Vlds[(r * 256 + w * 64) * 8]);
    }

    bf16x8 aq[2][2];
    #pragma unroll
    for (int mi = 0; mi < 2; ++mi)
      #pragma unroll
      for (int kd = 0; kd < 2; ++kd)
        aq[mi][kd] = *reinterpret_cast<const bf16x8*>(
            Qbase + (size_t)(w * 32 + mi * 16 + l4) * 2176 + kd * 32 + g * 8);

    __syncthreads();

    const f32x4 vz = {0.f, 0.f, 0.f, 0.f};
    float l_r[2] = {0.f, 0.f};
    f32x4 acc_o[2][4];
    #pragma unroll
    for (int mi = 0; mi < 2; ++mi)
      #pragma unroll
      for (int nd = 0; nd < 4; ++nd) acc_o[mi][nd] = vz;

    for (int kt = 0; kt < 32; ++kt) {
      const int cur = kt & 1;
      if (kt < 31) {
        const int kn = kt + 1;
        #pragma unroll
        for (int r = 0; r < 2; ++r) {
          const int sl = r * 256 + t, row = sl >> 3, blk = sl & 7;
          const int srcb = blk ^ (row & 7);
          const int prow = (row & 32) | (((row >> 2) & 3) << 3) | (((row >> 4) & 1) << 2) | (row & 3);
          gld_lds16(Kbase + (size_t)(kn * 64 + prow) * 2176 + srcb * 8,
                    &Klds[(cur ^ 1) * 4096 + (r * 256 + w * 64) * 8]);
          gld_lds16(Vbase + (size_t)row * 2048 + kn * 64 + srcb * 8,
                    &Vlds[(cur ^ 1) * 4096 + (r * 256 + w * 64) * 8]);
        }
      }
      // S^T = mfma(K_frag, Q_frag)
      f32x4 sc[2][4];
      #pragma unroll
      for (int mi = 0; mi < 2; ++mi)
        #pragma unroll
        for (int ni = 0; ni < 4; ++ni) sc[mi][ni] = vz;
      #pragma unroll
      for (int kd = 0; kd < 2; ++kd) {
        bf16x8 bk[4];
        #pragma unroll
        for (int ni = 0; ni < 4; ++ni) {
          const int row = ni * 16 + l4;
          const int blk = (kd * 4 + g) ^ (row & 7);
          bk[ni] = *reinterpret_cast<const bf16x8*>(&Klds[cur * 4096 + row * 64 + blk * 8]);
        }
        __builtin_amdgcn_s_setprio(1);
        #pragma unroll
        for (int mi = 0; mi < 2; ++mi)
          #pragma unroll
          for (int ni = 0; ni < 4; ++ni)
            sc[mi][ni] = __builtin_amdgcn_mfma_f32_16x16x32_bf16(bk[ni], aq[mi][kd],
                                                                 sc[mi][ni], 0, 0, 0);
        __builtin_amdgcn_s_setprio(0);
      }
      // in-register softmax
      unsigned pw[2][4][2];
      #pragma unroll
      for (int mi = 0; mi < 2; ++mi) {
        float rs = 0.f;
        #pragma unroll
        for (int ni = 0; ni < 4; ++ni) {
          const float a0 = __expf(sc[mi][ni][0] * 0.125f);
          const float a1 = __expf(sc[mi][ni][1] * 0.125f);
          const float a2 = __expf(sc[mi][ni][2] * 0.125f);
          const float a3 = __expf(sc[mi][ni][3] * 0.125f);
          rs += (a0 + a1) + (a2 + a3);
          pw[mi][ni][0] = cvtpk(a0, a1);
          pw[mi][ni][1] = cvtpk(a2, a3);
        }
        rs += __shfl_xor(rs, 16);
        rs += __shfl_xor(rs, 32);
        l_r[mi] += rs;
      }
      // O += P V
      #pragma unroll
      for (int ks = 0; ks < 2; ++ks) {
        bf16x8 bv[4];
        #pragma unroll
        for (int nd = 0; nd < 4; ++nd) {
          const int row = nd * 16 + l4;
          const int blk = (ks * 4 + g) ^ (row & 7);
          bv[nd] = *reinterpret_cast<const bf16x8*>(&Vlds[cur * 4096 + row * 64 + blk * 8]);
        }
        __builtin_amdgcn_s_setprio(1);
        #pragma unroll
        for (int mi = 0; mi < 2; ++mi) {
          const u32x4 aw = {pw[mi][2 * ks][0], pw[mi][2 * ks][1],
                            pw[mi][2 * ks + 1][0], pw[mi][2 * ks + 1][1]};
          const bf16x8 ap = __builtin_bit_cast(bf16x8, aw);
          #pragma unroll
          for (int nd = 0; nd < 4; ++nd)
            acc_o[mi][nd] = __builtin_amdgcn_mfma_f32_16x16x32_bf16(ap, bv[nd],
                                                                    acc_o[mi][nd], 0, 0, 0);
        }
        __builtin_amdgcn_s_setprio(0);
      }
      __syncthreads();
    }
    // epilogue
    float linv[2][4];
    #pragma unroll
    for (int mi = 0; mi < 2; ++mi)
      #pragma unroll
      for (int r = 0; r < 4; ++r) {
        const int src = (lane & 48) + ((lane & 48) >> 2) + r;
        linv[mi][r] = 1.0f / __shfl(l_r[mi], src);
      }
    #pragma unroll
    for (int mi = 0; mi < 2; ++mi)
      #pragma unroll
      for (int nd = 0; nd < 4; ++nd)
        #pragma unroll
        for (int r = 0; r < 4; ++r) {
          const int grow = b * 2048 + q0 + w * 32 + mi * 16 + g * 4 + r;
          const int gcol = h * 64 + nd * 16 + l4;
          Ao[(size_t)grow * 1088 + gcol] = f2bf(acc_o[mi][nd][r] * linv[mi][r]);
        }
    return;
  }

  // ================= secondary (R12 body; LDS: KsL | VtL | Plds)
  u16* KsL = sm;             // [2048*4]
  u16* VtL = sm + 8192;      // [5*2056]
  u16* Plds = sm + 18472;    // [4][2048]
  const int sid = (grp >> 1) * 8 + sub;       // [0,512)
  const int q0 = (sid & 15) * 128, h = (sid >> 4) & 15, b = sid >> 8;

  const u16* Vsrc = Vst + (size_t)((b * 16 + h) * 4) * 2048;
  #pragma unroll
  for (int r = 0; r < 4; ++r)
    gld_lds16(Vsrc + (size_t)r * 2048 + t * 8, &VtL[r * 2056 + w * 512]);
  {
    u16x8 ones;
    #pragma unroll
    for (int j = 0; j < 8; ++j) ones[j] = 0x3F80;
    *reinterpret_cast<u16x8*>(&VtL[4 * 2056 + t * 8]) = ones;
  }
  #pragma unroll
  for (int i = 0; i < 8; ++i) {
    const int s = i * 256 + t;
    const uint2 kk = *reinterpret_cast<const uint2*>(
        QKs + (size_t)(b * 2048 + s) * 2176 + 2112 + h * 4);
    *reinterpret_cast<uint2*>(&KsL[s * 4]) = kk;
  }
  bf16x8 aq[2];
  #pragma unroll
  for (int mi = 0; mi < 2; ++mi) {
    u16x8 qv = {0, 0, 0, 0, 0, 0, 0, 0};
    if (g == 0) {
      const uint2 qq = *reinterpret_cast<const uint2*>(
          QKs + (size_t)(b * 2048 + q0 + w * 32 + mi * 16 + l4) * 2176 + 2048 + h * 4);
      qv[0] = (u16)(qq.x & 0xffff); qv[1] = (u16)(qq.x >> 16);
      qv[2] = (u16)(qq.y & 0xffff); qv[3] = (u16)(qq.y >> 16);
    }
    aq[mi] = __builtin_bit_cast(bf16x8, qv);
  }
  __syncthreads();

  const f32x4 vz = {0.f, 0.f, 0.f, 0.f};
  f32x4 acc[2];
  acc[0] = vz; acc[1] = vz;

  for (int kt = 0; kt < 32; ++kt) {
    f32x4 sc[2][4];
    bf16x8 bk[4];
    #pragma unroll
    for (int ni = 0; ni < 4; ++ni) {
      u16x8 kv = {0, 0, 0, 0, 0, 0, 0, 0};
      if (g == 0) {
        const uint2 kk = *reinterpret_cast<const uint2*>(
            &KsL[(kt * 64 + ni * 16 + l4) * 4]);
        kv[0] = (u16)(kk.x & 0xffff); kv[1] = (u16)(kk.x >> 16);
        kv[2] = (u16)(kk.y & 0xffff); kv[3] = (u16)(kk.y >> 16);
      }
      bk[ni] = __builtin_bit_cast(bf16x8, kv);
    }
    #pragma unroll
    for (int mi = 0; mi < 2; ++mi)
      #pragma unroll
      for (int ni = 0; ni < 4; ++ni)
        sc[mi][ni] = __builtin_amdgcn_mfma_f32_16x16x32_bf16(aq[mi], bk[ni], vz, 0, 0, 0);
    #pragma unroll
    for (int mi = 0; mi < 2; ++mi)
      #pragma unroll
      for (int r = 0; r < 4; ++r) {
        const int prow = mi * 16 + g * 4 + r;
        #pragma unroll
        for (int ni = 0; ni < 4; ++ni) {
          const float p = __expf(sc[mi][ni][r] * 0.5f);
          const int col = ni * 16 + l4;
          Plds[w * 2048 + prow * 64 + ((col >> 3) ^ (prow & 7)) * 8 + (col & 7)] = f2bf(p);
        }
      }
    asm volatile("s_waitcnt lgkmcnt(0)" ::: "memory");
    #pragma unroll
    for (int ks = 0; ks < 2; ++ks) {
      const int blko = kt * 8 + ks * 4 + g;
      const int vrow = (l4 < 4) ? l4 : 4;
      const bf16x8 bv = *reinterpret_cast<const bf16x8*>(&VtL[vrow * 2056 + blko * 8]);
      #pragma unroll
      for (int mi = 0; mi < 2; ++mi) {
        const int row = mi * 16 + l4;
        const int blk = (ks * 4 + g) ^ (row & 7);
        const bf16x8 ap = *reinterpret_cast<const bf16x8*>(&Plds[w * 2048 + row * 64 + blk * 8]);
        acc[mi] = __builtin_amdgcn_mfma_f32_16x16x32_bf16(ap, bv, acc[mi], 0, 0, 0);
      }
    }
  }
  #pragma unroll
  for (int mi = 0; mi < 2; ++mi)
    #pragma unroll
    for (int r = 0; r < 4; ++r) {
      const float lsum = __shfl(acc[mi][r], (lane & 48) + 4);
      if (l4 < 4) {
        const int grow = b * 2048 + q0 + w * 32 + mi * 16 + g * 4 + r;
        Ao[(size_t)grow * 1088 + 1024 + h * 4 + l4] = f2bf(acc[mi][r] / lsum);
      }
    }
}

// ---------------- launch ----------------
extern "C" void kernel_launch(void* const* d_in, const int* in_sizes, int n_in,
                              void* d_out, int out_size, void* d_ws, size_t ws_size,
                              hipStream_t stream) {
  (void)in_sizes; (void)n_in; (void)out_size; (void)ws_size;
  const float* x    = (const float*)d_in[0];
  const float* wq_p = (const float*)d_in[1];
  const float* bq_p = (const float*)d_in[2];
  const float* wk_p = (const float*)d_in[3];
  const float* bk_p = (const float*)d_in[4];
  const float* wv_p = (const float*)d_in[5];
  const float* bv_p = (const float*)d_in[6];
  const float* wo_p = (const float*)d_in[7];
  const float* bo_p = (const float*)d_in[8];
  const float* wq_s = (const float*)d_in[9];
  const float* bq_s = (const float*)d_in[10];
  const float* wk_s = (const float*)d_in[11];
  const float* bk_s = (const float*)d_in[12];
  const float* wv_s = (const float*)d_in[13];
  const float* bv_s = (const float*)d_in[14];
  const float* wo_s = (const float*)d_in[15];
  const float* bo_s = (const float*)d_in[16];
  const float* wcr  = (const float*)d_in[17];

  char* p = (char*)d_ws;
  auto take = [&](size_t bytes) { char* r = p; p += (bytes + 255) & ~(size_t)255; return r; };
  u16* xb      = (u16*)take((size_t)4096 * 1024 * 2);
  u16* Wall    = (u16*)take((size_t)2176 * 1024 * 2);   // [Wq_p|Wk_p|wq_s|wk_s]
  u16* Wvt     = (u16*)take((size_t)1024 * 1024 * 2);
  u16* Wvst    = (u16*)take((size_t)64 * 1024 * 2);
  u16* Bto     = (u16*)take((size_t)1024 * 1088 * 2);
  float* ballqk= (float*)take(2176 * 4);
  float* bfin  = (float*)take(1024 * 4);
  u16* QKs     = (u16*)take((size_t)4096 * 2176 * 2);
  u16* Vpt     = (u16*)take((size_t)4096 * 1024 * 2);
  u16* Vst     = (u16*)take((size_t)2 * 16 * 4 * 2048 * 2);
  u16* Ao      = (u16*)take((size_t)4096 * 1088 * 2);

  k_prep<<<6409, 256, 0, stream>>>(x, wq_p, wk_p, wv_p, wo_p, wq_s, wk_s, wv_s, wo_s,
                                   bq_p, bk_p, bq_s, bk_s, bo_p, bo_s, wcr,
                                   xb, Wall, Wvt, Wvst, Bto, ballqk, bfin);

  k_proj3<<<832, 256, 0, stream>>>(xb, Wall, Wvt, Wvst, ballqk, bv_p, bv_s,
                                   QKs, Vpt, Vst);

  k_attn<<<1024, 256, 0, stream>>>(QKs, Vpt, Vst, Ao);

  k_gemm_final<<<dim3(32, 8), 256, 0, stream>>>(Ao, Bto, bfin, (float*)d_out);
}

// Round 15
// 152.747 us; speedup vs baseline: 1.4576x; 1.0136x over previous
//
#include <hip/hip_runtime.h>
#include <stdint.h>

typedef unsigned short u16;
typedef __bf16 bf16x8 __attribute__((ext_vector_type(8)));
typedef float f32x4 __attribute__((ext_vector_type(4)));
typedef u16 u16x8 __attribute__((ext_vector_type(8)));
typedef u16 u16x4 __attribute__((ext_vector_type(4)));
typedef unsigned u32x4 __attribute__((ext_vector_type(4)));

// B=2, S=2048, D=1024, H=16, HD=64, R=4. MS = B*S = 4096.
// QKs layout: [4096][2176] = [Q_p (1024) | K_p (1024) | q_s (64) | k_s (64)]

__device__ __forceinline__ u16 f2bf(float f) {
  unsigned u = __builtin_bit_cast(unsigned, f);
  u += 0x7FFFu + ((u >> 16) & 1u);          // RNE
  return (u16)(u >> 16);
}
__device__ __forceinline__ unsigned cvtpk(float lo, float hi) {
  unsigned r;
  asm("v_cvt_pk_bf16_f32 %0, %1, %2" : "=v"(r) : "v"(lo), "v"(hi));
  return r;
}
__device__ __forceinline__ void gld_lds16(const void* g, void* l) {
  __builtin_amdgcn_global_load_lds((__attribute__((address_space(1))) void*)(g),
                                   (__attribute__((address_space(3))) void*)(l),
                                   16, 0, 0);
}

// ---------------- fused prep: conv_x | 4 big transposes | 4 small transposes | bias ------
__global__ __launch_bounds__(256)
void k_prep(const float* __restrict__ x,
            const float* __restrict__ wq_p, const float* __restrict__ wk_p,
            const float* __restrict__ wv_p, const float* __restrict__ wo_p,
            const float* __restrict__ wq_s, const float* __restrict__ wk_s,
            const float* __restrict__ wv_s, const float* __restrict__ wo_s,
            const float* __restrict__ bq_p, const float* __restrict__ bk_p,
            const float* __restrict__ bq_s, const float* __restrict__ bk_s,
            const float* __restrict__ bo_p, const float* __restrict__ bo_s,
            const float* __restrict__ wcr,
            u16* __restrict__ xb, u16* __restrict__ Wall, u16* __restrict__ Wvt,
            u16* __restrict__ Wvst, u16* __restrict__ Bto,
            float* __restrict__ ballqk, float* __restrict__ bfin) {
  const int id = blockIdx.x;
  if (id < 2048) {                     // ---- x -> bf16
    const int i = id * 256 + threadIdx.x;
    const float4* p = reinterpret_cast<const float4*>(x) + (size_t)i * 2;
    float4 a = p[0], b = p[1];
    u16x8 o;
    o[0] = f2bf(a.x); o[1] = f2bf(a.y); o[2] = f2bf(a.z); o[3] = f2bf(a.w);
    o[4] = f2bf(b.x); o[5] = f2bf(b.y); o[6] = f2bf(b.z); o[7] = f2bf(b.w);
    *reinterpret_cast<u16x8*>(xb + (size_t)i * 8) = o;
    return;
  }
  if (id < 6400) {                     // ---- transposes
    __shared__ float tile[32][33];
    const int tx = threadIdx.x & 31, ty = threadIdx.x >> 5;  // 32x8
    const float* src; u16* dst; int N, ldd, n0, k0; float sc = 1.f;
    if (id < 6144) {                   // big: 4 jobs x 1024 tiles (N=1024)
      const int tid = id - 2048, job = tid >> 10, t10 = tid & 1023;
      switch (job) {
        case 0: src = wq_p; dst = Wall;                       ldd = 1024; break;
        case 1: src = wk_p; dst = Wall + (size_t)1024 * 1024; ldd = 1024; break;
        case 2: src = wv_p; dst = Wvt;                        ldd = 1024; break;
        default: src = wo_p; dst = Bto;                       ldd = 1088; break;
      }
      N = 1024; n0 = (t10 & 31) * 32; k0 = (t10 >> 5) * 32;
    } else {                           // small: 4 jobs x 64 tiles
      const int tid = id - 6144, job = tid >> 6, t6 = tid & 63;
      int ntx;
      switch (job) {
        case 0: src = wq_s; dst = Wall + (size_t)2048 * 1024; N = 64;   ldd = 1024; ntx = 2; break;
        case 1: src = wk_s; dst = Wall + (size_t)2112 * 1024; N = 64;   ldd = 1024; ntx = 2; break;
        case 2: src = wv_s; dst = Wvst;                       N = 64;   ldd = 1024; ntx = 2; break;
        default: src = wo_s; dst = Bto + 1024;                N = 1024; ldd = 1088; ntx = 32; sc = wcr[0]; break;
      }
      n0 = (t6 % ntx) * 32; k0 = (t6 / ntx) * 32;
    }
    #pragma unroll
    for (int i = 0; i < 4; ++i)
      tile[ty + i * 8][tx] = src[(size_t)(k0 + ty + i * 8) * N + n0 + tx];
    __syncthreads();
    #pragma unroll
    for (int i = 0; i < 4; ++i)
      dst[(size_t)(n0 + ty + i * 8) * ldd + k0 + tx] = f2bf(tile[tx][ty + i * 8] * sc);
    return;
  }
  // ---- bias prep
  const int i = (id - 6400) * 256 + threadIdx.x;
  if (i < 1024)       ballqk[i] = bq_p[i];
  else if (i < 2048)  ballqk[i] = bk_p[i - 1024];
  else if (i < 2112)  ballqk[i] = bq_s[i - 2048];
  else if (i < 2176)  ballqk[i] = bk_s[i - 2112];
  if (i < 1024) bfin[i] = bo_p[i] + wcr[0] * bo_s[i];
}

// ---------------- GEMM body (device fn over LDS carve) ----------------
// BM=128, BK=32, double-buffered single-barrier k-loop (R12-proven).
template <int BN, int WAVES_M, int OUTMODE, int OHD>
__device__ __forceinline__
void gemm_body(const u16* __restrict__ A, int lda,
               const u16* __restrict__ Bt, int ldb,
               const float* __restrict__ bias,
               void* __restrict__ Cv, int ldc, int K,
               int bx, int by, u16* sm) {
  constexpr int WM = 128 / WAVES_M;
  constexpr int MF = WM / 16;
  u16* Atile = sm;                 // [2][4096]
  u16* Btile = sm + 8192;          // [2][BN*32]
  const int t = threadIdx.x, w = t >> 6;
  const int lane = t & 63, l4 = lane & 15, g = lane >> 4;
  const int wr = (WAVES_M == 4) ? w : (w >> 1);
  const int wc = (WAVES_M == 4) ? 0 : (w & 1);
  const int m0 = bx * 128, n0 = by * BN;

  auto stage = [&](int buf, int kt) {
    const int k0 = kt * 32;
    #pragma unroll
    for (int r = 0; r < 2; ++r) {
      const int slot = r * 256 + t;
      const int row = slot >> 2, blk = slot & 3;
      const int srcb = blk ^ ((row >> 1) & 3);
      gld_lds16(A + (size_t)(m0 + row) * lda + k0 + srcb * 8,
                &Atile[buf * 4096 + (r * 256 + w * 64) * 8]);
    }
    #pragma unroll
    for (int r = 0; r < BN / 64; ++r) {
      const int slot = r * 256 + t;
      const int row = slot >> 2, blk = slot & 3;
      const int srcb = blk ^ ((row >> 1) & 3);
      gld_lds16(Bt + (size_t)(n0 + row) * ldb + k0 + srcb * 8,
                &Btile[buf * (BN * 32) + (r * 256 + w * 64) * 8]);
    }
  };

  const f32x4 vz = {0.f, 0.f, 0.f, 0.f};
  f32x4 acc[MF][4];
  #pragma unroll
  for (int mi = 0; mi < MF; ++mi)
    #pragma unroll
    for (int ni = 0; ni < 4; ++ni) acc[mi][ni] = vz;

  const int nkt = K >> 5;
  stage(0, 0);
  __syncthreads();
  for (int kt = 0; kt < nkt; ++kt) {
    const int cur = kt & 1;
    if (kt + 1 < nkt) stage(cur ^ 1, kt + 1);   // prefetch overlaps compute below
    bf16x8 af[MF], bfv[4];
    #pragma unroll
    for (int mi = 0; mi < MF; ++mi) {
      const int row = wr * WM + mi * 16 + l4;
      const int blk = g ^ ((row >> 1) & 3);
      af[mi] = *reinterpret_cast<const bf16x8*>(&Atile[cur * 4096 + row * 32 + blk * 8]);
    }
    #pragma unroll
    for (int ni = 0; ni < 4; ++ni) {
      const int row = wc * 64 + ni * 16 + l4;
      const int blk = g ^ ((row >> 1) & 3);
      bfv[ni] = *reinterpret_cast<const bf16x8*>(&Btile[cur * (BN * 32) + row * 32 + blk * 8]);
    }
    #pragma unroll
    for (int mi = 0; mi < MF; ++mi)
      #pragma unroll
      for (int ni = 0; ni < 4; ++ni)
        acc[mi][ni] = __builtin_amdgcn_mfma_f32_16x16x32_bf16(af[mi], bfv[ni],
                                                              acc[mi][ni], 0, 0, 0);
    __syncthreads();
  }
  // epilogue. C/D layout: col = lane&15, row = (lane>>4)*4 + reg
  #pragma unroll
  for (int mi = 0; mi < MF; ++mi) {
    #pragma unroll
    for (int ni = 0; ni < 4; ++ni) {
      const int grow0 = m0 + wr * WM + mi * 16 + g * 4;
      const int gcol = n0 + wc * 64 + ni * 16 + l4;
      const float bb = bias ? bias[gcol] : 0.f;
      if constexpr (OUTMODE == 1) {
        const int bidx = grow0 >> 11, s0 = grow0 & 2047;
        const int hh = gcol / OHD, dd = gcol % OHD;
        u16x4 ov;
        #pragma unroll
        for (int r = 0; r < 4; ++r) ov[r] = f2bf(acc[mi][ni][r] + bb);
        *reinterpret_cast<u16x4*>((u16*)Cv +
            (size_t)((bidx * 16 + hh) * OHD + dd) * 2048 + s0) = ov;
      } else {
        #pragma unroll
        for (int r = 0; r < 4; ++r) {
          const float v = acc[mi][ni][r] + bb;
          if constexpr (OUTMODE == 0)
            ((u16*)Cv)[(size_t)(grow0 + r) * ldc + gcol] = f2bf(v);
          else
            ((float*)Cv)[(size_t)(grow0 + r) * ldc + gcol] = v;
        }
      }
    }
  }
}

// ---------------- fused projections: [0,544) QK | [544,800) V | [800,832) Vst ------------
__global__ __launch_bounds__(256, 2)
void k_proj3(const u16* __restrict__ xb, const u16* __restrict__ Wall,
             const u16* __restrict__ Wvt, const u16* __restrict__ Wvst,
             const float* __restrict__ ballqk, const float* __restrict__ bv_p,
             const float* __restrict__ bv_s,
             u16* __restrict__ QKs, u16* __restrict__ Vpt, u16* __restrict__ Vst) {
  __shared__ __attribute__((aligned(16))) u16 sm[16384];  // 32KB (max of branches)
  const int id = blockIdx.x;
  if (id < 544) {
    gemm_body<128, 2, 0, 64>(xb, 1024, Wall, 1024, ballqk, QKs, 2176, 1024,
                             id & 31, id >> 5, sm);
  } else if (id < 800) {
    const int lid = id - 544;
    gemm_body<128, 2, 1, 64>(xb, 1024, Wvt, 1024, bv_p, Vpt, 0, 1024,
                             lid & 31, lid >> 5, sm);
  } else {
    const int lid = id - 800;
    gemm_body<64, 4, 1, 4>(xb, 1024, Wvst, 1024, bv_s, Vst, 0, 1024,
                           lid & 31, lid >> 5, sm);
  }
}

// ---------------- final GEMM wrapper ----------------
__global__ __launch_bounds__(256, 2)
void k_gemm_final(const u16* __restrict__ A, const u16* __restrict__ Bt,
                  const float* __restrict__ bias, float* __restrict__ C) {
  __shared__ __attribute__((aligned(16))) u16 sm[16384];
  gemm_body<128, 2, 2, 64>(A, 1088, Bt, 1088, bias, C, 1024, 1088,
                           blockIdx.x, blockIdx.y, sm);
}

// ---------------- fused attention, CU-paired interleave ----------------
// Blocks in groups of 8: even group -> primary, odd -> secondary (id%8 preserved).
// BOTH paths now use the R7-proven swapped-QK^T + permuted-K in-register-P scheme:
// no Plds, no fence; secondary loop is barrier-free (K/V staged once).
// LDS union 32.8KB -> up to 4 blocks/CU.
__global__ __launch_bounds__(256, 2)
void k_attn(const u16* __restrict__ QKs, const u16* __restrict__ Vpt,
            const u16* __restrict__ Vst, u16* __restrict__ Ao) {
  __shared__ __attribute__((aligned(16))) u16 sm[16416];  // 32.8KB union
  const int t = threadIdx.x, w = t >> 6;
  const int lane = t & 63, l4 = lane & 15, g = lane >> 4;
  const int grp = blockIdx.x >> 3, sub = blockIdx.x & 7;

  if ((grp & 1) == 0) {
    // ================= primary (R12 body; LDS: Klds=sm[0..8191], Vlds=sm[8192..16383])
    u16* Klds = sm;          // [2][4096]
    u16* Vlds = sm + 8192;   // [2][4096]
    const int id = (grp >> 1) * 8 + sub;      // [0,512)
    const int lin = (id & 7) * 64 + (id >> 3);
    const int qt = lin & 15, hb = lin >> 4;
    const int h = hb & 15, b = hb >> 4;
    const int q0 = qt * 128;

    const u16* Qbase = QKs + (size_t)(b * 2048 + q0) * 2176 + h * 64;
    const u16* Kbase = QKs + (size_t)(b * 2048) * 2176 + 1024 + h * 64;
    const u16* Vbase = Vpt + (size_t)((b * 16 + h) * 64) * 2048;

    #pragma unroll
    for (int r = 0; r < 2; ++r) {  // K (row-permuted), V tile 0 -> buf 0
      const int sl = r * 256 + t, row = sl >> 3, blk = sl & 7;
      const int srcb = blk ^ (row & 7);
      const int prow = (row & 32) | (((row >> 2) & 3) << 3) | (((row >> 4) & 1) << 2) | (row & 3);
      gld_lds16(Kbase + (size_t)prow * 2176 + srcb * 8, &Klds[(r * 256 + w * 64) * 8]);
      gld_lds16(Vbase + (size_t)row * 2048 + srcb * 8, &Vlds[(r * 256 + w * 64) * 8]);
    }

    bf16x8 aq[2][2];
    #pragma unroll
    for (int mi = 0; mi < 2; ++mi)
      #pragma unroll
      for (int kd = 0; kd < 2; ++kd)
        aq[mi][kd] = *reinterpret_cast<const bf16x8*>(
            Qbase + (size_t)(w * 32 + mi * 16 + l4) * 2176 + kd * 32 + g * 8);

    __syncthreads();

    const f32x4 vz = {0.f, 0.f, 0.f, 0.f};
    float l_r[2] = {0.f, 0.f};
    f32x4 acc_o[2][4];
    #pragma unroll
    for (int mi = 0; mi < 2; ++mi)
      #pragma unroll
      for (int nd = 0; nd < 4; ++nd) acc_o[mi][nd] = vz;

    for (int kt = 0; kt < 32; ++kt) {
      const int cur = kt & 1;
      if (kt < 31) {
        const int kn = kt + 1;
        #pragma unroll
        for (int r = 0; r < 2; ++r) {
          const int sl = r * 256 + t, row = sl >> 3, blk = sl & 7;
          const int srcb = blk ^ (row & 7);
          const int prow = (row & 32) | (((row >> 2) & 3) << 3) | (((row >> 4) & 1) << 2) | (row & 3);
          gld_lds16(Kbase + (size_t)(kn * 64 + prow) * 2176 + srcb * 8,
                    &Klds[(cur ^ 1) * 4096 + (r * 256 + w * 64) * 8]);
          gld_lds16(Vbase + (size_t)row * 2048 + kn * 64 + srcb * 8,
                    &Vlds[(cur ^ 1) * 4096 + (r * 256 + w * 64) * 8]);
        }
      }
      // S^T = mfma(K_frag, Q_frag)
      f32x4 sc[2][4];
      #pragma unroll
      for (int mi = 0; mi < 2; ++mi)
        #pragma unroll
        for (int ni = 0; ni < 4; ++ni) sc[mi][ni] = vz;
      #pragma unroll
      for (int kd = 0; kd < 2; ++kd) {
        bf16x8 bk[4];
        #pragma unroll
        for (int ni = 0; ni < 4; ++ni) {
          const int row = ni * 16 + l4;
          const int blk = (kd * 4 + g) ^ (row & 7);
          bk[ni] = *reinterpret_cast<const bf16x8*>(&Klds[cur * 4096 + row * 64 + blk * 8]);
        }
        __builtin_amdgcn_s_setprio(1);
        #pragma unroll
        for (int mi = 0; mi < 2; ++mi)
          #pragma unroll
          for (int ni = 0; ni < 4; ++ni)
            sc[mi][ni] = __builtin_amdgcn_mfma_f32_16x16x32_bf16(bk[ni], aq[mi][kd],
                                                                 sc[mi][ni], 0, 0, 0);
        __builtin_amdgcn_s_setprio(0);
      }
      // in-register softmax
      unsigned pw[2][4][2];
      #pragma unroll
      for (int mi = 0; mi < 2; ++mi) {
        float rs = 0.f;
        #pragma unroll
        for (int ni = 0; ni < 4; ++ni) {
          const float a0 = __expf(sc[mi][ni][0] * 0.125f);
          const float a1 = __expf(sc[mi][ni][1] * 0.125f);
          const float a2 = __expf(sc[mi][ni][2] * 0.125f);
          const float a3 = __expf(sc[mi][ni][3] * 0.125f);
          rs += (a0 + a1) + (a2 + a3);
          pw[mi][ni][0] = cvtpk(a0, a1);
          pw[mi][ni][1] = cvtpk(a2, a3);
        }
        rs += __shfl_xor(rs, 16);
        rs += __shfl_xor(rs, 32);
        l_r[mi] += rs;
      }
      // O += P V
      #pragma unroll
      for (int ks = 0; ks < 2; ++ks) {
        bf16x8 bv[4];
        #pragma unroll
        for (int nd = 0; nd < 4; ++nd) {
          const int row = nd * 16 + l4;
          const int blk = (ks * 4 + g) ^ (row & 7);
          bv[nd] = *reinterpret_cast<const bf16x8*>(&Vlds[cur * 4096 + row * 64 + blk * 8]);
        }
        __builtin_amdgcn_s_setprio(1);
        #pragma unroll
        for (int mi = 0; mi < 2; ++mi) {
          const u32x4 aw = {pw[mi][2 * ks][0], pw[mi][2 * ks][1],
                            pw[mi][2 * ks + 1][0], pw[mi][2 * ks + 1][1]};
          const bf16x8 ap = __builtin_bit_cast(bf16x8, aw);
          #pragma unroll
          for (int nd = 0; nd < 4; ++nd)
            acc_o[mi][nd] = __builtin_amdgcn_mfma_f32_16x16x32_bf16(ap, bv[nd],
                                                                    acc_o[mi][nd], 0, 0, 0);
        }
        __builtin_amdgcn_s_setprio(0);
      }
      __syncthreads();
    }
    // epilogue
    float linv[2][4];
    #pragma unroll
    for (int mi = 0; mi < 2; ++mi)
      #pragma unroll
      for (int r = 0; r < 4; ++r) {
        const int src = (lane & 48) + ((lane & 48) >> 2) + r;
        linv[mi][r] = 1.0f / __shfl(l_r[mi], src);
      }
    #pragma unroll
    for (int mi = 0; mi < 2; ++mi)
      #pragma unroll
      for (int nd = 0; nd < 4; ++nd)
        #pragma unroll
        for (int r = 0; r < 4; ++r) {
          const int grow = b * 2048 + q0 + w * 32 + mi * 16 + g * 4 + r;
          const int gcol = h * 64 + nd * 16 + l4;
          Ao[(size_t)grow * 1088 + gcol] = f2bf(acc_o[mi][nd][r] * linv[mi][r]);
        }
    return;
  }

  // ================= secondary: swapped QK^T + permuted K slots, in-register P ==========
  // LDS: KsL = sm[0..8191] (permuted slots), VtL = sm[8192..16415] (4 rows x 2056).
  // Barrier-free k-loop; denominator = register row-sum (no ones-row).
  u16* KsL = sm;             // [2048*4]
  u16* VtL = sm + 8192;      // [4][2056]
  const int sid = (grp >> 1) * 8 + sub;       // [0,512)
  const int q0 = (sid & 15) * 128, h = (sid >> 4) & 15, b = sid >> 8;

  const u16* Vsrc = Vst + (size_t)((b * 16 + h) * 4) * 2048;
  #pragma unroll
  for (int r = 0; r < 4; ++r)
    gld_lds16(Vsrc + (size_t)r * 2048 + t * 8, &VtL[r * 2056 + w * 512]);
  #pragma unroll
  for (int i = 0; i < 8; ++i) {  // K_s -> permuted slots (inverse of primary's k(p))
    const int s = i * 256 + t;
    const uint2 kk = *reinterpret_cast<const uint2*>(
        QKs + (size_t)(b * 2048 + s) * 2176 + 2112 + h * 4);
    const int slot = (s & ~31) | (((s >> 2) & 1) << 4) | (((s >> 3) & 3) << 2) | (s & 3);
    *reinterpret_cast<uint2*>(&KsL[slot * 4]) = kk;
  }
  bf16x8 aq[2];  // Q (B-operand): lane l4 = q-col, g==0 words 0..3 hold d 0..3
  #pragma unroll
  for (int mi = 0; mi < 2; ++mi) {
    u16x8 qv = {0, 0, 0, 0, 0, 0, 0, 0};
    if (g == 0) {
      const uint2 qq = *reinterpret_cast<const uint2*>(
          QKs + (size_t)(b * 2048 + q0 + w * 32 + mi * 16 + l4) * 2176 + 2048 + h * 4);
      qv[0] = (u16)(qq.x & 0xffff); qv[1] = (u16)(qq.x >> 16);
      qv[2] = (u16)(qq.y & 0xffff); qv[3] = (u16)(qq.y >> 16);
    }
    aq[mi] = __builtin_bit_cast(bf16x8, qv);
  }
  __syncthreads();

  const f32x4 vz = {0.f, 0.f, 0.f, 0.f};
  float l_r[2] = {0.f, 0.f};
  f32x4 acc[2];
  acc[0] = vz; acc[1] = vz;

  for (int kt = 0; kt < 32; ++kt) {
    bf16x8 bk[4];  // K (A-operand): lane l4 = permuted row, g==0 holds d 0..3
    #pragma unroll
    for (int ni = 0; ni < 4; ++ni) {
      u16x8 kv = {0, 0, 0, 0, 0, 0, 0, 0};
      if (g == 0) {
        const uint2 kk = *reinterpret_cast<const uint2*>(
            &KsL[(kt * 64 + ni * 16 + l4) * 4]);
        kv[0] = (u16)(kk.x & 0xffff); kv[1] = (u16)(kk.x >> 16);
        kv[2] = (u16)(kk.y & 0xffff); kv[3] = (u16)(kk.y >> 16);
      }
      bk[ni] = __builtin_bit_cast(bf16x8, kv);
    }
    // S^T = mfma(K, Q): lane (l4,g) reg r = P[q=l4][slot ni*16+4g+r] (true k = 32ks+8g+4o+r)
    f32x4 sc[2][4];
    #pragma unroll
    for (int mi = 0; mi < 2; ++mi)
      #pragma unroll
      for (int ni = 0; ni < 4; ++ni)
        sc[mi][ni] = __builtin_amdgcn_mfma_f32_16x16x32_bf16(bk[ni], aq[mi], vz, 0, 0, 0);
    // in-register softmax (row-sum -> denominator)
    unsigned pw[2][4][2];
    #pragma unroll
    for (int mi = 0; mi < 2; ++mi) {
      float rs = 0.f;
      #pragma unroll
      for (int ni = 0; ni < 4; ++ni) {
        const float a0 = __expf(sc[mi][ni][0] * 0.5f);
        const float a1 = __expf(sc[mi][ni][1] * 0.5f);
        const float a2 = __expf(sc[mi][ni][2] * 0.5f);
        const float a3 = __expf(sc[mi][ni][3] * 0.5f);
        rs += (a0 + a1) + (a2 + a3);
        pw[mi][ni][0] = cvtpk(a0, a1);
        pw[mi][ni][1] = cvtpk(a2, a3);
      }
      rs += __shfl_xor(rs, 16);
      rs += __shfl_xor(rs, 32);
      l_r[mi] += rs;
    }
    // O += P V (A-frag direct from cvt_pk words; V^T row = l4 (d), cols = k-block)
    #pragma unroll
    for (int ks = 0; ks < 2; ++ks) {
      const int blko = kt * 8 + ks * 4 + g;
      const int vrow = l4 & 3;   // only l4<4 columns are stored; clamp keeps reads in-bounds
      const bf16x8 bv = *reinterpret_cast<const bf16x8*>(&VtL[vrow * 2056 + blko * 8]);
      #pragma unroll
      for (int mi = 0; mi < 2; ++mi) {
        const u32x4 aw = {pw[mi][2 * ks][0], pw[mi][2 * ks][1],
                          pw[mi][2 * ks + 1][0], pw[mi][2 * ks + 1][1]};
        const bf16x8 ap = __builtin_bit_cast(bf16x8, aw);
        acc[mi] = __builtin_amdgcn_mfma_f32_16x16x32_bf16(ap, bv, acc[mi], 0, 0, 0);
      }
    }
  }
  // epilogue: O[q=4g+r+16mi][d=l4] / l(q); denominator via shfl from lane l4 = 4g+r
  #pragma unroll
  for (int mi = 0; mi < 2; ++mi)
    #pragma unroll
    for (int r = 0; r < 4; ++r) {
      const int src = (lane & 48) + ((lane & 48) >> 2) + r;
      const float linv = 1.0f / __shfl(l_r[mi], src);
      if (l4 < 4) {
        const int grow = b * 2048 + q0 + w * 32 + mi * 16 + g * 4 + r;
        Ao[(size_t)grow * 1088 + 1024 + h * 4 + l4] = f2bf(acc[mi][r] * linv);
      }
    }
}

// ---------------- launch ----------------
extern "C" void kernel_launch(void* const* d_in, const int* in_sizes, int n_in,
                              void* d_out, int out_size, void* d_ws, size_t ws_size,
                              hipStream_t stream) {
  (void)in_sizes; (void)n_in; (void)out_size; (void)ws_size;
  const float* x    = (const float*)d_in[0];
  const float* wq_p = (const float*)d_in[1];
  const float* bq_p = (const float*)d_in[2];
  const float* wk_p = (const float*)d_in[3];
  const float* bk_p = (const float*)d_in[4];
  const float* wv_p = (const float*)d_in[5];
  const float* bv_p = (const float*)d_in[6];
  const float* wo_p = (const float*)d_in[7];
  const float* bo_p = (const float*)d_in[8];
  const float* wq_s = (const float*)d_in[9];
  const float* bq_s = (const float*)d_in[10];
  const float* wk_s = (const float*)d_in[11];
  const float* bk_s = (const float*)d_in[12];
  const float* wv_s = (const float*)d_in[13];
  const float* bv_s = (const float*)d_in[14];
  const float* wo_s = (const float*)d_in[15];
  const float* bo_s = (const float*)d_in[16];
  const float* wcr  = (const float*)d_in[17];

  char* p = (char*)d_ws;
  auto take = [&](size_t bytes) { char* r = p; p += (bytes + 255) & ~(size_t)255; return r; };
  u16* xb      = (u16*)take((size_t)4096 * 1024 * 2);
  u16* Wall    = (u16*)take((size_t)2176 * 1024 * 2);   // [Wq_p|Wk_p|wq_s|wk_s]
  u16* Wvt     = (u16*)take((size_t)1024 * 1024 * 2);
  u16* Wvst    = (u16*)take((size_t)64 * 1024 * 2);
  u16* Bto     = (u16*)take((size_t)1024 * 1088 * 2);
  float* ballqk= (float*)take(2176 * 4);
  float* bfin  = (float*)take(1024 * 4);
  u16* QKs     = (u16*)take((size_t)4096 * 2176 * 2);
  u16* Vpt     = (u16*)take((size_t)4096 * 1024 * 2);
  u16* Vst     = (u16*)take((size_t)2 * 16 * 4 * 2048 * 2);
  u16* Ao      = (u16*)take((size_t)4096 * 1088 * 2);

  k_prep<<<6409, 256, 0, stream>>>(x, wq_p, wk_p, wv_p, wo_p, wq_s, wk_s, wv_s, wo_s,
                                   bq_p, bk_p, bq_s, bk_s, bo_p, bo_s, wcr,
                                   xb, Wall, Wvt, Wvst, Bto, ballqk, bfin);

  k_proj3<<<832, 256, 0, stream>>>(xb, Wall, Wvt, Wvst, ballqk, bv_p, bv_s,
                                   QKs, Vpt, Vst);

  k_attn<<<1024, 256, 0, stream>>>(QKs, Vpt, Vst, Ao);

  k_gemm_final<<<dim3(32, 8), 256, 0, stream>>>(Ao, Bto, bfin, (float*)d_out);
}